// Round 1
// baseline (656.492 us; speedup 1.0000x reference)
//
#include <hip/hip_runtime.h>

#define B_ 64
#define N_ 4096
#define D_ 256
#define S_ 8
#define EPSL 1e-5f

typedef _Float16 f16x8 __attribute__((ext_vector_type(8)));
typedef _Float16 f16x4 __attribute__((ext_vector_type(4)));
typedef float f32x4 __attribute__((ext_vector_type(4)));

// ---------------- LN(x) -> xn fp16 ----------------
__global__ __launch_bounds__(256) void k_ln_x(const float* __restrict__ x,
        const float* __restrict__ g, const float* __restrict__ be,
        _Float16* __restrict__ xn) {
    int w = threadIdx.x >> 6, l = threadIdx.x & 63;
    long row = (long)blockIdx.x * 4 + w;   // < 262144
    float4 xv = *(const float4*)(x + row * D_ + l * 4);
    float s = xv.x + xv.y + xv.z + xv.w;
    float q = xv.x*xv.x + xv.y*xv.y + xv.z*xv.z + xv.w*xv.w;
    #pragma unroll
    for (int m = 1; m < 64; m <<= 1) { s += __shfl_xor(s, m); q += __shfl_xor(q, m); }
    float mean = s * (1.0f/D_);
    float var = q * (1.0f/D_) - mean*mean;
    float inv = rsqrtf(var + EPSL);
    float4 gv = *(const float4*)(g + l*4);
    float4 bv = *(const float4*)(be + l*4);
    f16x4 o;
    o[0] = (_Float16)((xv.x-mean)*inv*gv.x + bv.x);
    o[1] = (_Float16)((xv.y-mean)*inv*gv.y + bv.y);
    o[2] = (_Float16)((xv.z-mean)*inv*gv.z + bv.z);
    o[3] = (_Float16)((xv.w-mean)*inv*gv.w + bv.w);
    *(f16x4*)(xn + row * D_ + l*4) = o;
}

// ---------------- slots init + zero qh16 ----------------
__global__ __launch_bounds__(256) void k_slot_init(const float* __restrict__ noise,
        const float* __restrict__ mu, const float* __restrict__ sg,
        float* __restrict__ slots, unsigned int* __restrict__ qh_zero) {
    int tid = blockIdx.x*256 + threadIdx.x;  // < 131072
    int d = tid & 255;
    slots[tid] = mu[d] + __expf(sg[d]) * noise[tid];
    qh_zero[tid] = 0u;   // zero all of qh16 (rows 8..15 stay zero forever)
}

// ---------------- per-slot: LN -> q -> qh (fp16) ----------------
__global__ __launch_bounds__(256) void k_slotprep(const float* __restrict__ slots,
     const float* __restrict__ g, const float* __restrict__ be,
     const float* __restrict__ Wq, const float* __restrict__ bq,
     const float* __restrict__ Wk, _Float16* __restrict__ qh16) {
    __shared__ float sn[D_], ql[D_], red[10];
    int t = threadIdx.x, w = t>>6, l = t&63;
    long base = (long)blockIdx.x * D_;   // blockIdx = b*8+s, 512 blocks
    float v = slots[base + t];
    float s = v, q = v*v;
    #pragma unroll
    for (int m=1;m<64;m<<=1){ s+=__shfl_xor(s,m); q+=__shfl_xor(q,m);}
    if (l==0){ red[w]=s; red[4+w]=q; }
    __syncthreads();
    if (t==0){
        float ss=red[0]+red[1]+red[2]+red[3];
        float qq=red[4]+red[5]+red[6]+red[7];
        float mean = ss*(1.0f/D_); float var = qq*(1.0f/D_) - mean*mean;
        red[8]=mean; red[9]=rsqrtf(var+EPSL);
    }
    __syncthreads();
    float mean=red[8], inv=red[9];
    sn[t] = (v-mean)*inv*g[t] + be[t];
    __syncthreads();
    float acc = bq[t];
    const float4* wr = (const float4*)(Wq + (long)t*D_);
    const float4* sv = (const float4*)sn;
    for (int e=0;e<64;e++){ float4 a=wr[e], b=sv[e];
        acc += a.x*b.x + a.y*b.y + a.z*b.z + a.w*b.w; }
    ql[t]=acc;
    __syncthreads();
    float qh=0.f;
    for (int e=0;e<D_;e++) qh += ql[e]*Wk[(long)e*D_ + t];
    qh16[((long)(blockIdx.x>>3)*16 + (blockIdx.x&7))*D_ + t] = (_Float16)qh;
}

// ---------------- logits = qh . xn  (MFMA f16, M=16 pad of S=8) ----------------
__global__ __launch_bounds__(256) void k_logits(const _Float16* __restrict__ xn,
        const _Float16* __restrict__ qh16, float* __restrict__ logits,
        float* __restrict__ lmax) {
    int t = threadIdx.x, w = t>>6, l = t&63;
    int chunk = blockIdx.x;      // 0..15 -> 256 n each
    int b = blockIdx.y;          // 0..63
    int lr = l & 15, lh = l >> 4;
    f16x8 A[8];
    const _Float16* qbase = qh16 + ((long)b*16 + lr)*D_ + lh*8;
    #pragma unroll
    for (int ks=0;ks<8;ks++) A[ks] = *(const f16x8*)(qbase + ks*32);
    float vmax[4] = {-1e30f,-1e30f,-1e30f,-1e30f};
    __shared__ float lm[4][8];
    for (int p=0;p<4;p++){
        int n0 = chunk*256 + p*64 + w*16;
        f32x4 acc = {0.f,0.f,0.f,0.f};
        const _Float16* xb = xn + ((long)b*N_ + n0 + lr)*D_ + lh*8;
        #pragma unroll
        for (int ks=0;ks<8;ks++){
            f16x8 Bf = *(const f16x8*)(xb + ks*32);
            acc = __builtin_amdgcn_mfma_f32_16x16x32_f16(A[ks], Bf, acc, 0,0,0);
        }
        if (lh < 2){
            #pragma unroll
            for (int r=0;r<4;r++){
                int srow = lh*4 + r;   // slot
                logits[((long)b*8 + srow)*N_ + n0 + lr] = acc[r];
                vmax[r] = fmaxf(vmax[r], acc[r]);
            }
        }
    }
    #pragma unroll
    for (int m=1;m<16;m<<=1){
        #pragma unroll
        for (int r=0;r<4;r++) vmax[r] = fmaxf(vmax[r], __shfl_xor(vmax[r], m));
    }
    if (lr==0 && lh<2){
        #pragma unroll
        for (int r=0;r<4;r++) lm[w][lh*4+r] = vmax[r];
    }
    __syncthreads();
    if (t < 8){
        float m = fmaxf(fmaxf(lm[0][t], lm[1][t]), fmaxf(lm[2][t], lm[3][t]));
        lmax[((long)b*16 + chunk)*8 + t] = m;
    }
}

// ---------------- exp + axpy: partial acc[s][d] = sum_n exp(l-gmax)*xn[n][d] ----------------
__global__ __launch_bounds__(256) void k_axpy(const _Float16* __restrict__ xn,
        const float* __restrict__ logits, const float* __restrict__ lmax,
        float* __restrict__ pacc, float* __restrict__ ppsum) {
    int t = threadIdx.x, g = t>>6, l = t&63;
    int c = blockIdx.x, b = blockIdx.y;    // c: 0..7 -> 512 n each
    __shared__ float gm[8];
    __shared__ float accl[4][8][256];
    __shared__ float psl[4][8];
    if (t < 8){
        float m = -1e30f;
        for (int k=0;k<16;k++) m = fmaxf(m, lmax[((long)b*16+k)*8 + t]);
        gm[t] = m;
    }
    __syncthreads();
    float g8[8];
    #pragma unroll
    for (int s=0;s<8;s++) g8[s] = gm[s];
    float acc[8][4] = {};
    float ps[8] = {};
    int nbase = c*512 + g*128;
    const _Float16* xb = xn + ((long)b*N_ + nbase)*D_ + l*4;
    for (int i=0;i<128;i++){
        int n = nbase + i;
        float p[8];
        #pragma unroll
        for (int s=0;s<8;s++){
            float lg = logits[((long)b*8+s)*N_ + n];
            p[s] = __expf(lg - g8[s]);
            ps[s] += p[s];
        }
        f16x4 xv = *(const f16x4*)(xb + (long)i*D_);
        float xf0=(float)xv[0], xf1=(float)xv[1], xf2=(float)xv[2], xf3=(float)xv[3];
        #pragma unroll
        for (int s=0;s<8;s++){
            acc[s][0] += p[s]*xf0; acc[s][1] += p[s]*xf1;
            acc[s][2] += p[s]*xf2; acc[s][3] += p[s]*xf3;
        }
    }
    #pragma unroll
    for (int s=0;s<8;s++)
        *(float4*)&accl[g][s][l*4] = *(const float4*)acc[s];
    if (l==0){
        #pragma unroll
        for (int s=0;s<8;s++) psl[g][s] = ps[s];
    }
    __syncthreads();
    for (int pair = t; pair < 2048; pair += 256){
        int s = pair >> 8, d = pair & 255;
        float v = accl[0][s][d]+accl[1][s][d]+accl[2][s][d]+accl[3][s][d];
        pacc[(((long)b*8 + c)*8 + s)*D_ + d] = v;
    }
    if (t < 8){
        float v = psl[0][t]+psl[1][t]+psl[2][t]+psl[3][t];
        ppsum[((long)b*8+c)*8 + t] = v;
    }
}

// ---------------- tail: reduce -> @Wv^T+bv -> GRU -> LN -> MLP -> slots ----------------
__global__ __launch_bounds__(256) void k_tail(
    const float* __restrict__ pacc, const float* __restrict__ ppsum,
    const float* __restrict__ slots,
    const float* __restrict__ Wv, const float* __restrict__ bv,
    const float* __restrict__ Wih, const float* __restrict__ bih,
    const float* __restrict__ Whh, const float* __restrict__ bhh,
    const float* __restrict__ W1, const float* __restrict__ b1,
    const float* __restrict__ W2, const float* __restrict__ b2,
    const float* __restrict__ gm, const float* __restrict__ bem,
    float* __restrict__ out) {
    int t = threadIdx.x, w=t>>6, l=t&63;
    int b = blockIdx.x;
    __shared__ float ax[8][256], hb[8][256], ul[8][256], hn[8][256], ml[8][256], hl[8][256];
    __shared__ float pss[8];
    __shared__ float2 mv[8];
    if (t<8){
        float v=0; for (int c=0;c<8;c++) v += ppsum[((long)b*8+c)*8+t];
        pss[t]=v;
    }
    __syncthreads();
    #pragma unroll
    for (int s=0;s<8;s++){
        float v=0;
        for (int c=0;c<8;c++) v += pacc[(((long)b*8+c)*8+s)*D_ + t];
        ax[s][t] = v / pss[s];
        hb[s][t] = slots[((long)b*8+s)*D_ + t];
    }
    __syncthreads();
    float us[8];
    {   float bvt = bv[t];
        #pragma unroll
        for (int s=0;s<8;s++) us[s]=bvt;
        const float4* wr = (const float4*)(Wv + (long)t*D_);
        for (int e4=0;e4<64;e4++){
            float4 wv4 = wr[e4];
            #pragma unroll
            for (int s=0;s<8;s++){
                const float* a = &ax[s][e4*4];
                us[s] += wv4.x*a[0] + wv4.y*a[1] + wv4.z*a[2] + wv4.w*a[3];
            }
        }
    }
    #pragma unroll
    for (int s=0;s<8;s++) ul[s][t]=us[s];
    __syncthreads();
    float gx[3][8]={}, gh[3][8]={};
    for (int g3=0;g3<3;g3++){
        const float4* wih = (const float4*)(Wih + (long)(g3*256+t)*D_);
        const float4* whh = (const float4*)(Whh + (long)(g3*256+t)*D_);
        for (int e4=0;e4<64;e4++){
            float4 wi = wih[e4], wh = whh[e4];
            #pragma unroll
            for (int s=0;s<8;s++){
                const float* u = &ul[s][e4*4];
                const float* h = &hb[s][e4*4];
                gx[g3][s] += wi.x*u[0]+wi.y*u[1]+wi.z*u[2]+wi.w*u[3];
                gh[g3][s] += wh.x*h[0]+wh.y*h[1]+wh.z*h[2]+wh.w*h[3];
            }
        }
    }
    float bi0=bih[t], bi1=bih[256+t], bi2=bih[512+t];
    float bh0=bhh[t], bh1=bhh[256+t], bh2=bhh[512+t];
    #pragma unroll
    for (int s=0;s<8;s++){
        float r = 1.f/(1.f+__expf(-(gx[0][s]+bi0 + gh[0][s]+bh0)));
        float z = 1.f/(1.f+__expf(-(gx[1][s]+bi1 + gh[1][s]+bh1)));
        float nn = tanhf(gx[2][s]+bi2 + r*(gh[2][s]+bh2));
        hn[s][t] = (1.f-z)*nn + z*hb[s][t];
    }
    __syncthreads();
    for (int rr = w*2; rr < w*2+2; rr++){
        float4 hv = *(const float4*)&hn[rr][l*4];
        float s1 = hv.x+hv.y+hv.z+hv.w;
        float s2 = hv.x*hv.x+hv.y*hv.y+hv.z*hv.z+hv.w*hv.w;
        #pragma unroll
        for (int m=1;m<64;m<<=1){ s1+=__shfl_xor(s1,m); s2+=__shfl_xor(s2,m);}
        if (l==0){ float mean=s1*(1.0f/D_); float var=s2*(1.0f/D_)-mean*mean;
                   mv[rr]=make_float2(mean, rsqrtf(var+EPSL)); }
    }
    __syncthreads();
    #pragma unroll
    for (int s=0;s<8;s++)
        ml[s][t] = (hn[s][t]-mv[s].x)*mv[s].y*gm[t] + bem[t];
    __syncthreads();
    {   float b1t = b1[t];
        float hid[8];
        #pragma unroll
        for (int s=0;s<8;s++) hid[s]=b1t;
        const float4* wr = (const float4*)(W1 + (long)t*D_);
        for (int e4=0;e4<64;e4++){
            float4 wv4 = wr[e4];
            #pragma unroll
            for (int s=0;s<8;s++){
                const float* a = &ml[s][e4*4];
                hid[s] += wv4.x*a[0]+wv4.y*a[1]+wv4.z*a[2]+wv4.w*a[3];
            }
        }
        #pragma unroll
        for (int s=0;s<8;s++) hl[s][t] = fmaxf(hid[s], 0.f);
    }
    __syncthreads();
    {   float b2t = b2[t];
        float o[8];
        #pragma unroll
        for (int s=0;s<8;s++) o[s] = hn[s][t] + b2t;
        const float4* wr = (const float4*)(W2 + (long)t*D_);
        for (int e4=0;e4<64;e4++){
            float4 wv4 = wr[e4];
            #pragma unroll
            for (int s=0;s<8;s++){
                const float* a = &hl[s][e4*4];
                o[s] += wv4.x*a[0]+wv4.y*a[1]+wv4.z*a[2]+wv4.w*a[3];
            }
        }
        #pragma unroll
        for (int s=0;s<8;s++) out[((long)b*8+s)*D_ + t] = o[s];
    }
}

extern "C" void kernel_launch(void* const* d_in, const int* in_sizes, int n_in,
                              void* d_out, int out_size, void* d_ws, size_t ws_size,
                              hipStream_t stream) {
    const float* x     = (const float*)d_in[0];
    const float* noise = (const float*)d_in[1];
    const float* mu    = (const float*)d_in[2];
    const float* sg    = (const float*)d_in[3];
    const float* Wq    = (const float*)d_in[4];
    const float* bq    = (const float*)d_in[5];
    const float* Wk    = (const float*)d_in[6];
    // d_in[7] = bk: provably softmax-invariant, unused
    const float* Wv    = (const float*)d_in[8];
    const float* bv    = (const float*)d_in[9];
    const float* Wih   = (const float*)d_in[10];
    const float* bih   = (const float*)d_in[11];
    const float* Whh   = (const float*)d_in[12];
    const float* bhh   = (const float*)d_in[13];
    const float* W1    = (const float*)d_in[14];
    const float* b1    = (const float*)d_in[15];
    const float* W2    = (const float*)d_in[16];
    const float* b2    = (const float*)d_in[17];
    const float* g_in  = (const float*)d_in[18];
    const float* be_in = (const float*)d_in[19];
    const float* g_sl  = (const float*)d_in[20];
    const float* be_sl = (const float*)d_in[21];
    const float* g_mlp = (const float*)d_in[22];
    const float* be_mlp= (const float*)d_in[23];

    char* ws = (char*)d_ws;
    _Float16* xn16  = (_Float16*)(ws);                   // 134217728 B
    _Float16* qh16  = (_Float16*)(ws + 134217728);       //    524288 B
    float*    slots = (float*)   (ws + 134742016);       //    524288 B
    float*    logits= (float*)   (ws + 135266304);       //   8388608 B
    float*    lmax  = (float*)   (ws + 143654912);       //     32768 B
    float*    pacc  = (float*)   (ws + 143687680);       //  16777216 B
    float*    ppsum = (float*)   (ws + 160464896);       //     16384 B

    hipLaunchKernelGGL(k_ln_x, dim3(65536), dim3(256), 0, stream, x, g_in, be_in, xn16);
    hipLaunchKernelGGL(k_slot_init, dim3(512), dim3(256), 0, stream, noise, mu, sg,
                       slots, (unsigned int*)qh16);
    for (int it = 0; it < 3; it++){
        hipLaunchKernelGGL(k_slotprep, dim3(512), dim3(256), 0, stream,
                           slots, g_sl, be_sl, Wq, bq, Wk, qh16);
        hipLaunchKernelGGL(k_logits, dim3(16,64), dim3(256), 0, stream,
                           xn16, qh16, logits, lmax);
        hipLaunchKernelGGL(k_axpy, dim3(8,64), dim3(256), 0, stream,
                           xn16, logits, lmax, pacc, ppsum);
        float* dst = (it==2) ? (float*)d_out : slots;
        hipLaunchKernelGGL(k_tail, dim3(64), dim3(256), 0, stream,
                           pacc, ppsum, slots, Wv, bv, Wih, bih, Whh, bhh,
                           W1, b1, W2, b2, g_mlp, be_mlp, dst);
    }
}

// Round 2
// 640.923 us; speedup vs baseline: 1.0243x; 1.0243x over previous
//
#include <hip/hip_runtime.h>

#define B_ 64
#define N_ 4096
#define D_ 256
#define S_ 8
#define EPSL 1e-5f

typedef _Float16 f16x8 __attribute__((ext_vector_type(8)));
typedef _Float16 f16x4 __attribute__((ext_vector_type(4)));
typedef float f32x4 __attribute__((ext_vector_type(4)));

// ---------------- LN(x) -> xn fp16 ----------------
__global__ __launch_bounds__(256) void k_ln_x(const float* __restrict__ x,
        const float* __restrict__ g, const float* __restrict__ be,
        _Float16* __restrict__ xn) {
    int w = threadIdx.x >> 6, l = threadIdx.x & 63;
    long row = (long)blockIdx.x * 4 + w;   // < 262144
    float4 xv = *(const float4*)(x + row * D_ + l * 4);
    float s = xv.x + xv.y + xv.z + xv.w;
    float q = xv.x*xv.x + xv.y*xv.y + xv.z*xv.z + xv.w*xv.w;
    #pragma unroll
    for (int m = 1; m < 64; m <<= 1) { s += __shfl_xor(s, m); q += __shfl_xor(q, m); }
    float mean = s * (1.0f/D_);
    float var = q * (1.0f/D_) - mean*mean;
    float inv = rsqrtf(var + EPSL);
    float4 gv = *(const float4*)(g + l*4);
    float4 bv = *(const float4*)(be + l*4);
    f16x4 o;
    o[0] = (_Float16)((xv.x-mean)*inv*gv.x + bv.x);
    o[1] = (_Float16)((xv.y-mean)*inv*gv.y + bv.y);
    o[2] = (_Float16)((xv.z-mean)*inv*gv.z + bv.z);
    o[3] = (_Float16)((xv.w-mean)*inv*gv.w + bv.w);
    *(f16x4*)(xn + row * D_ + l*4) = o;
}

// ---------------- slots init + zero qh16 ----------------
__global__ __launch_bounds__(256) void k_slot_init(const float* __restrict__ noise,
        const float* __restrict__ mu, const float* __restrict__ sg,
        float* __restrict__ slots, unsigned int* __restrict__ qh_zero) {
    int tid = blockIdx.x*256 + threadIdx.x;  // < 131072
    int d = tid & 255;
    slots[tid] = mu[d] + __expf(sg[d]) * noise[tid];
    qh_zero[tid] = 0u;   // zero all of qh16 (rows 8..15 stay zero forever)
}

// ---------------- initial per-slot: LN -> q -> qh (fp16) ----------------
__global__ __launch_bounds__(256) void k_slotprep(const float* __restrict__ slots,
     const float* __restrict__ g, const float* __restrict__ be,
     const float* __restrict__ Wq, const float* __restrict__ bq,
     const float* __restrict__ Wk, _Float16* __restrict__ qh16) {
    __shared__ float sn[D_], ql[D_], red[10];
    int t = threadIdx.x, w = t>>6, l = t&63;
    long base = (long)blockIdx.x * D_;   // blockIdx = b*8+s, 512 blocks
    float v = slots[base + t];
    float s = v, q = v*v;
    #pragma unroll
    for (int m=1;m<64;m<<=1){ s+=__shfl_xor(s,m); q+=__shfl_xor(q,m);}
    if (l==0){ red[w]=s; red[4+w]=q; }
    __syncthreads();
    if (t==0){
        float ss=red[0]+red[1]+red[2]+red[3];
        float qq=red[4]+red[5]+red[6]+red[7];
        float mean = ss*(1.0f/D_); float var = qq*(1.0f/D_) - mean*mean;
        red[8]=mean; red[9]=rsqrtf(var+EPSL);
    }
    __syncthreads();
    float mean=red[8], inv=red[9];
    sn[t] = (v-mean)*inv*g[t] + be[t];
    __syncthreads();
    float acc = bq[t];
    const float4* wr = (const float4*)(Wq + (long)t*D_);
    const float4* sv = (const float4*)sn;
    for (int e=0;e<64;e++){ float4 a=wr[e], b=sv[e];
        acc += a.x*b.x + a.y*b.y + a.z*b.z + a.w*b.w; }
    ql[t]=acc;
    __syncthreads();
    float qh=0.f;
    for (int e=0;e<D_;e++) qh += ql[e]*Wk[(long)e*D_ + t];
    qh16[((long)(blockIdx.x>>3)*16 + (blockIdx.x&7))*D_ + t] = (_Float16)qh;
}

// ---------------- fused: logits (MFMA) + online softmax + axpy ----------------
// block = (c 0..7, b 0..63), 256 thr. Block owns n in [c*512, c*512+512).
// Wave w owns rows  c*512 + sc*64 + w*16 .. +16  per sub-chunk sc (8 sub-chunks).
// Per-wave running max/sum; exact cross-wave/cross-block combine via pmax.
#define XPAD 264
__global__ __launch_bounds__(256) void k_attn(const _Float16* __restrict__ xn,
        const _Float16* __restrict__ qh16,
        float* __restrict__ pacc, float* __restrict__ ppsum,
        float* __restrict__ pmax) {
    __shared__ _Float16 xt_s[4][16][XPAD];   // 33792 B, reused as accw f32[4][8][256]
    __shared__ float pt_s[4][16][8];         // 2 KB
    __shared__ float mw_s[4][8];
    __shared__ float psw_s[4][8];
    int t = threadIdx.x, w = t>>6, l = t&63, lr = l&15, lh = l>>4;
    int c = blockIdx.x, b = blockIdx.y;

    f16x8 A[8];
    const _Float16* qbase = qh16 + ((long)b*16 + lr)*D_ + lh*8;
    #pragma unroll
    for (int ks=0;ks<8;ks++) A[ks] = *(const f16x8*)(qbase + ks*32);

    float m8[8];
    #pragma unroll
    for (int s=0;s<8;s++) m8[s] = -1e30f;
    float acc[8][4] = {};
    float psr[4] = {0.f,0.f,0.f,0.f};

    _Float16 (*xt)[XPAD] = xt_s[w];
    float (*pt)[8] = pt_s[w];

    for (int sc=0; sc<8; ++sc){
        int n0 = c*512 + sc*64 + w*16;
        const _Float16* xb = xn + ((long)b*N_ + n0 + lr)*D_ + lh*8;
        f32x4 lacc = {0.f,0.f,0.f,0.f};
        #pragma unroll
        for (int ks=0;ks<8;ks++){
            f16x8 Bf = *(const f16x8*)(xb + ks*32);
            *(f16x8*)&xt[lr][ks*32 + lh*8] = Bf;
            lacc = __builtin_amdgcn_mfma_f32_16x16x32_f16(A[ks], Bf, lacc, 0,0,0);
        }
        // tile max per s (valid in lanes lh<2: s=lh*4+r, n=n0+lr)
        float tm[4];
        #pragma unroll
        for (int r=0;r<4;r++) tm[r] = lacc[r];
        #pragma unroll
        for (int m=1;m<16;m<<=1){
            #pragma unroll
            for (int r=0;r<4;r++) tm[r] = fmaxf(tm[r], __shfl_xor(tm[r], m));
        }
        // broadcast tile max for s=0..7 to all lanes
        float mN[8];
        #pragma unroll
        for (int r=0;r<4;r++){ mN[r] = __shfl(tm[r], lr); mN[4+r] = __shfl(tm[r], 16+lr); }
        float sc8[8];
        #pragma unroll
        for (int s=0;s<8;s++){
            float mn = fmaxf(m8[s], mN[s]);
            sc8[s] = __expf(m8[s] - mn);
            m8[s] = mn;
        }
        #pragma unroll
        for (int s=0;s<8;s++){
            acc[s][0]*=sc8[s]; acc[s][1]*=sc8[s]; acc[s][2]*=sc8[s]; acc[s][3]*=sc8[s];
        }
        if (lh < 2){
            float4 pv;
            #pragma unroll
            for (int r=0;r<4;r++){
                int s = lh*4+r;
                float p = __expf(lacc[r] - m8[s]);
                psr[r] = psr[r]*sc8[s] + p;
                ((float*)&pv)[r] = p;
            }
            *(float4*)&pt[lr][lh*4] = pv;
        }
        __syncthreads();   // per-wave data, barrier is cheap insurance
        // phase B: axpy from LDS
        #pragma unroll 4
        for (int i=0;i<16;i++){
            float4 p0 = *(const float4*)&pt[i][0];
            float4 p1 = *(const float4*)&pt[i][4];
            f16x4 xv = *(const f16x4*)&xt[i][l*4];
            float x0=(float)xv[0], x1=(float)xv[1], x2=(float)xv[2], x3=(float)xv[3];
            acc[0][0]+=p0.x*x0; acc[0][1]+=p0.x*x1; acc[0][2]+=p0.x*x2; acc[0][3]+=p0.x*x3;
            acc[1][0]+=p0.y*x0; acc[1][1]+=p0.y*x1; acc[1][2]+=p0.y*x2; acc[1][3]+=p0.y*x3;
            acc[2][0]+=p0.z*x0; acc[2][1]+=p0.z*x1; acc[2][2]+=p0.z*x2; acc[2][3]+=p0.z*x3;
            acc[3][0]+=p0.w*x0; acc[3][1]+=p0.w*x1; acc[3][2]+=p0.w*x2; acc[3][3]+=p0.w*x3;
            acc[4][0]+=p1.x*x0; acc[4][1]+=p1.x*x1; acc[4][2]+=p1.x*x2; acc[4][3]+=p1.x*x3;
            acc[5][0]+=p1.y*x0; acc[5][1]+=p1.y*x1; acc[5][2]+=p1.y*x2; acc[5][3]+=p1.y*x3;
            acc[6][0]+=p1.z*x0; acc[6][1]+=p1.z*x1; acc[6][2]+=p1.z*x2; acc[6][3]+=p1.z*x3;
            acc[7][0]+=p1.w*x0; acc[7][1]+=p1.w*x1; acc[7][2]+=p1.w*x2; acc[7][3]+=p1.w*x3;
        }
    }
    // ---- combine across waves ----
    #pragma unroll
    for (int m=1;m<16;m<<=1){
        #pragma unroll
        for (int r=0;r<4;r++) psr[r] += __shfl_xor(psr[r], m);
    }
    if (l == 0){
        #pragma unroll
        for (int s=0;s<8;s++) mw_s[w][s] = m8[s];
        #pragma unroll
        for (int r=0;r<4;r++) psw_s[w][r] = psr[r];
    }
    if (l == 16){
        #pragma unroll
        for (int r=0;r<4;r++) psw_s[w][4+r] = psr[r];
    }
    __syncthreads();   // also guarantees all phase-B xt reads are done
    float M8[8];
    #pragma unroll
    for (int s=0;s<8;s++)
        M8[s] = fmaxf(fmaxf(mw_s[0][s],mw_s[1][s]), fmaxf(mw_s[2][s],mw_s[3][s]));
    float* accw = (float*)xt_s;   // [4][8][256] reuse
    #pragma unroll
    for (int s=0;s<8;s++){
        float wsc = __expf(m8[s] - M8[s]);
        float4 v;
        v.x=acc[s][0]*wsc; v.y=acc[s][1]*wsc; v.z=acc[s][2]*wsc; v.w=acc[s][3]*wsc;
        *(float4*)&accw[((w*8+s)<<8) + l*4] = v;
    }
    __syncthreads();
    for (int pair=t; pair<2048; pair+=256){
        int s = pair>>8, d = pair&255;
        float v = accw[(s<<8)+d] + accw[((8+s)<<8)+d] + accw[((16+s)<<8)+d] + accw[((24+s)<<8)+d];
        pacc[(((long)b*8 + c)*8 + s)*D_ + d] = v;
    }
    if (t < 8){
        float ps = 0.f;
        #pragma unroll
        for (int w2=0;w2<4;w2++) ps += __expf(mw_s[w2][t]-M8[t]) * psw_s[w2][t];
        ppsum[((long)b*8+c)*8 + t] = ps;
        pmax [((long)b*8+c)*8 + t] = M8[t];
    }
}

// ---------------- tail: combine -> @Wv^T+bv -> GRU -> LN -> MLP -> slots (+prep) ----
__global__ __launch_bounds__(256) void k_tail(
    const float* __restrict__ pacc, const float* __restrict__ ppsum,
    const float* __restrict__ pmax, const float* __restrict__ slots,
    const float* __restrict__ Wv, const float* __restrict__ bv,
    const float* __restrict__ Wih, const float* __restrict__ bih,
    const float* __restrict__ Whh, const float* __restrict__ bhh,
    const float* __restrict__ W1, const float* __restrict__ b1,
    const float* __restrict__ W2, const float* __restrict__ b2,
    const float* __restrict__ gm, const float* __restrict__ bem,
    const float* __restrict__ g_sl, const float* __restrict__ be_sl,
    const float* __restrict__ Wq, const float* __restrict__ bq,
    const float* __restrict__ Wk,
    float* __restrict__ out, _Float16* __restrict__ qh16, int last) {
    int t = threadIdx.x, w=t>>6, l=t&63;
    int b = blockIdx.x;
    __shared__ float ax[8][256], hb[8][256], ul[8][256], hn[8][256], ml[8][256], hl[8][256];
    __shared__ float pss[8], Mg[8];
    __shared__ float wcs[8][8];
    __shared__ float2 mv[8];
    if (t<8){
        float M=-1e30f;
        for (int c=0;c<8;c++) M = fmaxf(M, pmax[((long)b*8+c)*8+t]);
        Mg[t]=M;
    }
    __syncthreads();
    if (t<64){
        int s=t>>3, c=t&7;
        wcs[s][c] = __expf(pmax[((long)b*8+c)*8+s] - Mg[s]);
    }
    __syncthreads();
    if (t<8){
        float v=0.f;
        for (int c=0;c<8;c++) v += wcs[t][c]*ppsum[((long)b*8+c)*8+t];
        pss[t]=v;
    }
    __syncthreads();
    #pragma unroll
    for (int s=0;s<8;s++){
        float v=0.f;
        for (int c=0;c<8;c++) v += wcs[s][c]*pacc[(((long)b*8+c)*8+s)*D_ + t];
        ax[s][t] = v / pss[s];
        hb[s][t] = slots[((long)b*8+s)*D_ + t];
    }
    __syncthreads();
    float us[8];
    {   float bvt = bv[t];
        #pragma unroll
        for (int s=0;s<8;s++) us[s]=bvt;
        const float4* wr = (const float4*)(Wv + (long)t*D_);
        for (int e4=0;e4<64;e4++){
            float4 wv4 = wr[e4];
            #pragma unroll
            for (int s=0;s<8;s++){
                const float* a = &ax[s][e4*4];
                us[s] += wv4.x*a[0] + wv4.y*a[1] + wv4.z*a[2] + wv4.w*a[3];
            }
        }
    }
    #pragma unroll
    for (int s=0;s<8;s++) ul[s][t]=us[s];
    __syncthreads();
    float gx[3][8]={}, gh[3][8]={};
    for (int g3=0;g3<3;g3++){
        const float4* wih = (const float4*)(Wih + (long)(g3*256+t)*D_);
        const float4* whh = (const float4*)(Whh + (long)(g3*256+t)*D_);
        for (int e4=0;e4<64;e4++){
            float4 wi = wih[e4], wh = whh[e4];
            #pragma unroll
            for (int s=0;s<8;s++){
                const float* u = &ul[s][e4*4];
                const float* h = &hb[s][e4*4];
                gx[g3][s] += wi.x*u[0]+wi.y*u[1]+wi.z*u[2]+wi.w*u[3];
                gh[g3][s] += wh.x*h[0]+wh.y*h[1]+wh.z*h[2]+wh.w*h[3];
            }
        }
    }
    float bi0=bih[t], bi1=bih[256+t], bi2=bih[512+t];
    float bh0=bhh[t], bh1=bhh[256+t], bh2=bhh[512+t];
    #pragma unroll
    for (int s=0;s<8;s++){
        float r = 1.f/(1.f+__expf(-(gx[0][s]+bi0 + gh[0][s]+bh0)));
        float z = 1.f/(1.f+__expf(-(gx[1][s]+bi1 + gh[1][s]+bh1)));
        float nn = tanhf(gx[2][s]+bi2 + r*(gh[2][s]+bh2));
        hn[s][t] = (1.f-z)*nn + z*hb[s][t];
    }
    __syncthreads();
    for (int rr = w*2; rr < w*2+2; rr++){
        float4 hv = *(const float4*)&hn[rr][l*4];
        float s1 = hv.x+hv.y+hv.z+hv.w;
        float s2 = hv.x*hv.x+hv.y*hv.y+hv.z*hv.z+hv.w*hv.w;
        #pragma unroll
        for (int m=1;m<64;m<<=1){ s1+=__shfl_xor(s1,m); s2+=__shfl_xor(s2,m);}
        if (l==0){ float mean=s1*(1.0f/D_); float var=s2*(1.0f/D_)-mean*mean;
                   mv[rr]=make_float2(mean, rsqrtf(var+EPSL)); }
    }
    __syncthreads();
    #pragma unroll
    for (int s=0;s<8;s++)
        ml[s][t] = (hn[s][t]-mv[s].x)*mv[s].y*gm[t] + bem[t];
    __syncthreads();
    {   float b1t = b1[t];
        float hid[8];
        #pragma unroll
        for (int s=0;s<8;s++) hid[s]=b1t;
        const float4* wr = (const float4*)(W1 + (long)t*D_);
        for (int e4=0;e4<64;e4++){
            float4 wv4 = wr[e4];
            #pragma unroll
            for (int s=0;s<8;s++){
                const float* a = &ml[s][e4*4];
                hid[s] += wv4.x*a[0]+wv4.y*a[1]+wv4.z*a[2]+wv4.w*a[3];
            }
        }
        #pragma unroll
        for (int s=0;s<8;s++) hl[s][t] = fmaxf(hid[s], 0.f);
    }
    __syncthreads();
    float o[8];
    {   float b2t = b2[t];
        #pragma unroll
        for (int s=0;s<8;s++) o[s] = hn[s][t] + b2t;
        const float4* wr = (const float4*)(W2 + (long)t*D_);
        for (int e4=0;e4<64;e4++){
            float4 wv4 = wr[e4];
            #pragma unroll
            for (int s=0;s<8;s++){
                const float* a = &hl[s][e4*4];
                o[s] += wv4.x*a[0]+wv4.y*a[1]+wv4.z*a[2]+wv4.w*a[3];
            }
        }
        #pragma unroll
        for (int s=0;s<8;s++) out[((long)b*8+s)*D_ + t] = o[s];
    }
    if (!last){
        // fold next-iteration slot prep: LN -> q -> qh
        __syncthreads();
        #pragma unroll
        for (int s=0;s<8;s++) ml[s][t] = o[s];
        __syncthreads();
        for (int rr = w*2; rr < w*2+2; rr++){
            float4 hv = *(const float4*)&ml[rr][l*4];
            float s1 = hv.x+hv.y+hv.z+hv.w;
            float s2 = hv.x*hv.x+hv.y*hv.y+hv.z*hv.z+hv.w*hv.w;
            #pragma unroll
            for (int m=1;m<64;m<<=1){ s1+=__shfl_xor(s1,m); s2+=__shfl_xor(s2,m);}
            if (l==0){ float mean=s1*(1.0f/D_); float var=s2*(1.0f/D_)-mean*mean;
                       mv[rr]=make_float2(mean, rsqrtf(var+EPSL)); }
        }
        __syncthreads();
        #pragma unroll
        for (int s=0;s<8;s++)
            hl[s][t] = (ml[s][t]-mv[s].x)*mv[s].y*g_sl[t] + be_sl[t];
        __syncthreads();
        float qv[8];
        {   float bqt = bq[t];
            #pragma unroll
            for (int s=0;s<8;s++) qv[s]=bqt;
            const float4* wr = (const float4*)(Wq + (long)t*D_);
            for (int e4=0;e4<64;e4++){
                float4 wv4 = wr[e4];
                #pragma unroll
                for (int s=0;s<8;s++){
                    const float* a = &hl[s][e4*4];
                    qv[s] += wv4.x*a[0]+wv4.y*a[1]+wv4.z*a[2]+wv4.w*a[3];
                }
            }
        }
        __syncthreads();
        #pragma unroll
        for (int s=0;s<8;s++) ml[s][t] = qv[s];   // ql
        __syncthreads();
        float qh[8] = {};
        for (int e4=0;e4<64;e4++){
            float wk0 = Wk[(long)(e4*4+0)*D_ + t];
            float wk1 = Wk[(long)(e4*4+1)*D_ + t];
            float wk2 = Wk[(long)(e4*4+2)*D_ + t];
            float wk3 = Wk[(long)(e4*4+3)*D_ + t];
            #pragma unroll
            for (int s=0;s<8;s++){
                const float* q4 = &ml[s][e4*4];
                qh[s] += q4[0]*wk0 + q4[1]*wk1 + q4[2]*wk2 + q4[3]*wk3;
            }
        }
        #pragma unroll
        for (int s=0;s<8;s++)
            qh16[((long)b*16+s)*D_ + t] = (_Float16)qh[s];
    }
}

extern "C" void kernel_launch(void* const* d_in, const int* in_sizes, int n_in,
                              void* d_out, int out_size, void* d_ws, size_t ws_size,
                              hipStream_t stream) {
    const float* x     = (const float*)d_in[0];
    const float* noise = (const float*)d_in[1];
    const float* mu    = (const float*)d_in[2];
    const float* sg    = (const float*)d_in[3];
    const float* Wq    = (const float*)d_in[4];
    const float* bq    = (const float*)d_in[5];
    const float* Wk    = (const float*)d_in[6];
    // d_in[7] = bk: softmax-invariant, unused
    const float* Wv    = (const float*)d_in[8];
    const float* bv    = (const float*)d_in[9];
    const float* Wih   = (const float*)d_in[10];
    const float* bih   = (const float*)d_in[11];
    const float* Whh   = (const float*)d_in[12];
    const float* bhh   = (const float*)d_in[13];
    const float* W1    = (const float*)d_in[14];
    const float* b1    = (const float*)d_in[15];
    const float* W2    = (const float*)d_in[16];
    const float* b2    = (const float*)d_in[17];
    const float* g_in  = (const float*)d_in[18];
    const float* be_in = (const float*)d_in[19];
    const float* g_sl  = (const float*)d_in[20];
    const float* be_sl = (const float*)d_in[21];
    const float* g_mlp = (const float*)d_in[22];
    const float* be_mlp= (const float*)d_in[23];

    char* ws = (char*)d_ws;
    _Float16* xn16  = (_Float16*)(ws);                   // 134217728 B
    _Float16* qh16  = (_Float16*)(ws + 134217728);       //    524288 B
    float*    slots = (float*)   (ws + 134742016);       //    524288 B
    float*    pacc  = (float*)   (ws + 135266304);       //  16777216 B
    float*    ppsum = (float*)   (ws + 152043520);       //     16384 B
    float*    pmax  = (float*)   (ws + 152059904);       //     16384 B

    hipLaunchKernelGGL(k_ln_x, dim3(65536), dim3(256), 0, stream, x, g_in, be_in, xn16);
    hipLaunchKernelGGL(k_slot_init, dim3(512), dim3(256), 0, stream, noise, mu, sg,
                       slots, (unsigned int*)qh16);
    hipLaunchKernelGGL(k_slotprep, dim3(512), dim3(256), 0, stream,
                       slots, g_sl, be_sl, Wq, bq, Wk, qh16);
    for (int it = 0; it < 3; it++){
        hipLaunchKernelGGL(k_attn, dim3(8,64), dim3(256), 0, stream,
                           xn16, qh16, pacc, ppsum, pmax);
        float* dst = (it==2) ? (float*)d_out : slots;
        hipLaunchKernelGGL(k_tail, dim3(64), dim3(256), 0, stream,
                           pacc, ppsum, pmax, slots, Wv, bv, Wih, bih, Whh, bhh,
                           W1, b1, W2, b2, g_mlp, be_mlp,
                           g_sl, be_sl, Wq, bq, Wk,
                           dst, qh16, (it==2) ? 1 : 0);
    }
}

// Round 3
// 390.636 us; speedup vs baseline: 1.6806x; 1.6407x over previous
//
#include <hip/hip_runtime.h>

#define B_ 64
#define N_ 4096
#define D_ 256
#define S_ 8
#define EPSL 1e-5f

typedef _Float16 f16x8 __attribute__((ext_vector_type(8)));
typedef _Float16 f16x4 __attribute__((ext_vector_type(4)));
typedef float f32x4 __attribute__((ext_vector_type(4)));

// ---------------- LN(x) -> xn fp16 ----------------
__global__ __launch_bounds__(256) void k_ln_x(const float* __restrict__ x,
        const float* __restrict__ g, const float* __restrict__ be,
        _Float16* __restrict__ xn) {
    int w = threadIdx.x >> 6, l = threadIdx.x & 63;
    long row = (long)blockIdx.x * 4 + w;   // < 262144
    float4 xv = *(const float4*)(x + row * D_ + l * 4);
    float s = xv.x + xv.y + xv.z + xv.w;
    float q = xv.x*xv.x + xv.y*xv.y + xv.z*xv.z + xv.w*xv.w;
    #pragma unroll
    for (int m = 1; m < 64; m <<= 1) { s += __shfl_xor(s, m); q += __shfl_xor(q, m); }
    float mean = s * (1.0f/D_);
    float var = q * (1.0f/D_) - mean*mean;
    float inv = rsqrtf(var + EPSL);
    float4 gv = *(const float4*)(g + l*4);
    float4 bv = *(const float4*)(be + l*4);
    f16x4 o;
    o[0] = (_Float16)((xv.x-mean)*inv*gv.x + bv.x);
    o[1] = (_Float16)((xv.y-mean)*inv*gv.y + bv.y);
    o[2] = (_Float16)((xv.z-mean)*inv*gv.z + bv.z);
    o[3] = (_Float16)((xv.w-mean)*inv*gv.w + bv.w);
    *(f16x4*)(xn + row * D_ + l*4) = o;
}

// ---------------- slots init + zero qh16 ----------------
__global__ __launch_bounds__(256) void k_slot_init(const float* __restrict__ noise,
        const float* __restrict__ mu, const float* __restrict__ sg,
        float* __restrict__ slots, unsigned int* __restrict__ qh_zero) {
    int tid = blockIdx.x*256 + threadIdx.x;  // < 131072
    int d = tid & 255;
    slots[tid] = mu[d] + __expf(sg[d]) * noise[tid];
    qh_zero[tid] = 0u;   // zero all of qh16 (rows 8..15 stay zero forever)
}

// ---------------- weights -> f16 (and Wk transposed) ----------------
// layout (elems): Wv16@0(65536) Wih16@65536(196608) Whh16@262144(196608)
//                 W116@458752 W216@524288 Wq16@589824 WkT16@655360  total 720896
__global__ __launch_bounds__(256) void k_wprep(const float* __restrict__ Wv,
        const float* __restrict__ Wih, const float* __restrict__ Whh,
        const float* __restrict__ W1, const float* __restrict__ W2,
        const float* __restrict__ Wq, const float* __restrict__ Wk,
        _Float16* __restrict__ o) {
    long i = (long)blockIdx.x*256 + threadIdx.x;
    if (i < 65536)        o[i] = (_Float16)Wv[i];
    else if (i < 262144)  o[i] = (_Float16)Wih[i-65536];
    else if (i < 458752)  o[i] = (_Float16)Whh[i-262144];
    else if (i < 524288)  o[i] = (_Float16)W1[i-458752];
    else if (i < 589824)  o[i] = (_Float16)W2[i-524288];
    else if (i < 655360)  o[i] = (_Float16)Wq[i-589824];
    else if (i < 720896){ long j = i-655360; int d = (int)(j>>8), e = (int)(j&255);
                          o[i] = (_Float16)Wk[(long)e*256 + d]; }
}

// ---------------- initial per-slot: LN -> q -> qh (fp16) ----------------
__global__ __launch_bounds__(256) void k_slotprep(const float* __restrict__ slots,
     const float* __restrict__ g, const float* __restrict__ be,
     const float* __restrict__ Wq, const float* __restrict__ bq,
     const float* __restrict__ Wk, _Float16* __restrict__ qh16) {
    __shared__ float sn[D_], ql[D_], red[10];
    int t = threadIdx.x, w = t>>6, l = t&63;
    long base = (long)blockIdx.x * D_;   // blockIdx = b*8+s, 512 blocks
    float v = slots[base + t];
    float s = v, q = v*v;
    #pragma unroll
    for (int m=1;m<64;m<<=1){ s+=__shfl_xor(s,m); q+=__shfl_xor(q,m);}
    if (l==0){ red[w]=s; red[4+w]=q; }
    __syncthreads();
    if (t==0){
        float ss=red[0]+red[1]+red[2]+red[3];
        float qq=red[4]+red[5]+red[6]+red[7];
        float mean = ss*(1.0f/D_); float var = qq*(1.0f/D_) - mean*mean;
        red[8]=mean; red[9]=rsqrtf(var+EPSL);
    }
    __syncthreads();
    float mean=red[8], inv=red[9];
    sn[t] = (v-mean)*inv*g[t] + be[t];
    __syncthreads();
    float acc = bq[t];
    const float4* wr = (const float4*)(Wq + (long)t*D_);
    const float4* sv = (const float4*)sn;
    for (int e=0;e<64;e++){ float4 a=wr[e], b=sv[e];
        acc += a.x*b.x + a.y*b.y + a.z*b.z + a.w*b.w; }
    ql[t]=acc;
    __syncthreads();
    float qh=0.f;
    for (int e=0;e<D_;e++) qh += ql[e]*Wk[(long)e*D_ + t];
    qh16[((long)(blockIdx.x>>3)*16 + (blockIdx.x&7))*D_ + t] = (_Float16)qh;
}

// ---------------- fused: logits (MFMA) + online softmax + axpy ----------------
#define XPAD 264
__global__ __launch_bounds__(256) void k_attn(const _Float16* __restrict__ xn,
        const _Float16* __restrict__ qh16,
        float* __restrict__ pacc, float* __restrict__ ppsum,
        float* __restrict__ pmax) {
    __shared__ _Float16 xt_s[4][16][XPAD];   // 33792 B, reused as accw f32[4][8][256]
    __shared__ float pt_s[4][16][8];         // 2 KB
    __shared__ float mw_s[4][8];
    __shared__ float psw_s[4][8];
    int t = threadIdx.x, w = t>>6, l = t&63, lr = l&15, lh = l>>4;
    int c = blockIdx.x, b = blockIdx.y;

    f16x8 A[8];
    const _Float16* qbase = qh16 + ((long)b*16 + lr)*D_ + lh*8;
    #pragma unroll
    for (int ks=0;ks<8;ks++) A[ks] = *(const f16x8*)(qbase + ks*32);

    float m8[8];
    #pragma unroll
    for (int s=0;s<8;s++) m8[s] = -1e30f;
    float acc[8][4] = {};
    float psr[4] = {0.f,0.f,0.f,0.f};

    _Float16 (*xt)[XPAD] = xt_s[w];
    float (*pt)[8] = pt_s[w];

    for (int sc=0; sc<8; ++sc){
        int n0 = c*512 + sc*64 + w*16;
        const _Float16* xb = xn + ((long)b*N_ + n0 + lr)*D_ + lh*8;
        f32x4 lacc = {0.f,0.f,0.f,0.f};
        #pragma unroll
        for (int ks=0;ks<8;ks++){
            f16x8 Bf = *(const f16x8*)(xb + ks*32);
            *(f16x8*)&xt[lr][ks*32 + lh*8] = Bf;
            lacc = __builtin_amdgcn_mfma_f32_16x16x32_f16(A[ks], Bf, lacc, 0,0,0);
        }
        float tm[4];
        #pragma unroll
        for (int r=0;r<4;r++) tm[r] = lacc[r];
        #pragma unroll
        for (int m=1;m<16;m<<=1){
            #pragma unroll
            for (int r=0;r<4;r++) tm[r] = fmaxf(tm[r], __shfl_xor(tm[r], m));
        }
        float mN[8];
        #pragma unroll
        for (int r=0;r<4;r++){ mN[r] = __shfl(tm[r], lr); mN[4+r] = __shfl(tm[r], 16+lr); }
        float sc8[8];
        #pragma unroll
        for (int s=0;s<8;s++){
            float mn = fmaxf(m8[s], mN[s]);
            sc8[s] = __expf(m8[s] - mn);
            m8[s] = mn;
        }
        #pragma unroll
        for (int s=0;s<8;s++){
            acc[s][0]*=sc8[s]; acc[s][1]*=sc8[s]; acc[s][2]*=sc8[s]; acc[s][3]*=sc8[s];
        }
        if (lh < 2){
            float4 pv;
            #pragma unroll
            for (int r=0;r<4;r++){
                int s = lh*4+r;
                float p = __expf(lacc[r] - m8[s]);
                psr[r] = psr[r]*sc8[s] + p;
                ((float*)&pv)[r] = p;
            }
            *(float4*)&pt[lr][lh*4] = pv;
        }
        __syncthreads();
        #pragma unroll 4
        for (int i=0;i<16;i++){
            float4 p0 = *(const float4*)&pt[i][0];
            float4 p1 = *(const float4*)&pt[i][4];
            f16x4 xv = *(const f16x4*)&xt[i][l*4];
            float x0=(float)xv[0], x1=(float)xv[1], x2=(float)xv[2], x3=(float)xv[3];
            acc[0][0]+=p0.x*x0; acc[0][1]+=p0.x*x1; acc[0][2]+=p0.x*x2; acc[0][3]+=p0.x*x3;
            acc[1][0]+=p0.y*x0; acc[1][1]+=p0.y*x1; acc[1][2]+=p0.y*x2; acc[1][3]+=p0.y*x3;
            acc[2][0]+=p0.z*x0; acc[2][1]+=p0.z*x1; acc[2][2]+=p0.z*x2; acc[2][3]+=p0.z*x3;
            acc[3][0]+=p0.w*x0; acc[3][1]+=p0.w*x1; acc[3][2]+=p0.w*x2; acc[3][3]+=p0.w*x3;
            acc[4][0]+=p1.x*x0; acc[4][1]+=p1.x*x1; acc[4][2]+=p1.x*x2; acc[4][3]+=p1.x*x3;
            acc[5][0]+=p1.y*x0; acc[5][1]+=p1.y*x1; acc[5][2]+=p1.y*x2; acc[5][3]+=p1.y*x3;
            acc[6][0]+=p1.z*x0; acc[6][1]+=p1.z*x1; acc[6][2]+=p1.z*x2; acc[6][3]+=p1.z*x3;
            acc[7][0]+=p1.w*x0; acc[7][1]+=p1.w*x1; acc[7][2]+=p1.w*x2; acc[7][3]+=p1.w*x3;
        }
    }
    #pragma unroll
    for (int m=1;m<16;m<<=1){
        #pragma unroll
        for (int r=0;r<4;r++) psr[r] += __shfl_xor(psr[r], m);
    }
    if (l == 0){
        #pragma unroll
        for (int s=0;s<8;s++) mw_s[w][s] = m8[s];
        #pragma unroll
        for (int r=0;r<4;r++) psw_s[w][r] = psr[r];
    }
    if (l == 16){
        #pragma unroll
        for (int r=0;r<4;r++) psw_s[w][4+r] = psr[r];
    }
    __syncthreads();
    float M8[8];
    #pragma unroll
    for (int s=0;s<8;s++)
        M8[s] = fmaxf(fmaxf(mw_s[0][s],mw_s[1][s]), fmaxf(mw_s[2][s],mw_s[3][s]));
    float* accw = (float*)xt_s;   // [4][8][256] reuse
    #pragma unroll
    for (int s=0;s<8;s++){
        float wsc = __expf(m8[s] - M8[s]);
        float4 v;
        v.x=acc[s][0]*wsc; v.y=acc[s][1]*wsc; v.z=acc[s][2]*wsc; v.w=acc[s][3]*wsc;
        *(float4*)&accw[((w*8+s)<<8) + l*4] = v;
    }
    __syncthreads();
    for (int pair=t; pair<2048; pair+=256){
        int s = pair>>8, d = pair&255;
        float v = accw[(s<<8)+d] + accw[((8+s)<<8)+d] + accw[((16+s)<<8)+d] + accw[((24+s)<<8)+d];
        pacc[(((long)b*8 + c)*8 + s)*D_ + d] = v;
    }
    if (t < 8){
        float ps = 0.f;
        #pragma unroll
        for (int w2=0;w2<4;w2++) ps += __expf(mw_s[w2][t]-M8[t]) * psw_s[w2][t];
        ppsum[((long)b*8+c)*8 + t] = ps;
        pmax [((long)b*8+c)*8 + t] = M8[t];
    }
}

// ============ tail helpers: swizzled f16 A-tile in LDS ============
__device__ __forceinline__ void a16_st4(_Float16* a, int row, int col, float4 v){
    int byte = row*512 + ((col*2) ^ ((row&7)<<4));
    f16x4 h; h[0]=(_Float16)v.x; h[1]=(_Float16)v.y; h[2]=(_Float16)v.z; h[3]=(_Float16)v.w;
    *(f16x4*)((char*)a + byte) = h;
}
__device__ __forceinline__ f16x8 a16_ld8(const _Float16* a, int row, int col){
    int byte = row*512 + ((col*2) ^ ((row&7)<<4));
    return *(const f16x8*)((const char*)a + byte);
}

// out[s][n] = sum_k A[s][k] * W[n][k],  N = NT*16*4waves, K=256
template<int NT, int OS>
__device__ __forceinline__ void mm_stage(const _Float16* a16,
        const _Float16* __restrict__ Wg, float* outl, int w, int l){
    int lr = l&15, lh = l>>4;
    f16x8 A[8];
    #pragma unroll
    for (int ks=0;ks<8;ks++) A[ks] = a16_ld8(a16, lr, lh*8 + ks*32);
    #pragma unroll
    for (int tile=0; tile<NT; ++tile){
        int n0 = (w*NT + tile)*16;
        const _Float16* wb = Wg + (long)(n0+lr)*256 + lh*8;
        f32x4 acc = {0.f,0.f,0.f,0.f};
        #pragma unroll
        for (int ks=0;ks<8;ks++){
            f16x8 Bf = *(const f16x8*)(wb + ks*32);
            acc = __builtin_amdgcn_mfma_f32_16x16x32_f16(A[ks], Bf, acc, 0,0,0);
        }
        if (lh < 2){
            #pragma unroll
            for (int r=0;r<4;r++) outl[(lh*4+r)*OS + n0 + lr] = acc[r];
        }
    }
}

// gates: g1 = us@Wih^T, g2 = hb@Whh^T  (N=768 each, K=256)
__device__ __forceinline__ void mm_gates(const _Float16* au, const _Float16* ah,
        const _Float16* __restrict__ Wi, const _Float16* __restrict__ Wh,
        float* g1, float* g2, int w, int l){
    int lr = l&15, lh = l>>4;
    f16x8 Au[8], Ah[8];
    #pragma unroll
    for (int ks=0;ks<8;ks++){ Au[ks] = a16_ld8(au, lr, lh*8+ks*32);
                              Ah[ks] = a16_ld8(ah, lr, lh*8+ks*32); }
    #pragma unroll
    for (int tile=0; tile<12; ++tile){
        int n0 = (w*12 + tile)*16;
        const _Float16* wi = Wi + (long)(n0+lr)*256 + lh*8;
        const _Float16* wh = Wh + (long)(n0+lr)*256 + lh*8;
        f32x4 a1 = {0.f,0.f,0.f,0.f}, a2 = {0.f,0.f,0.f,0.f};
        #pragma unroll
        for (int ks=0;ks<8;ks++)
            a1 = __builtin_amdgcn_mfma_f32_16x16x32_f16(Au[ks], *(const f16x8*)(wi+ks*32), a1, 0,0,0);
        #pragma unroll
        for (int ks=0;ks<8;ks++)
            a2 = __builtin_amdgcn_mfma_f32_16x16x32_f16(Ah[ks], *(const f16x8*)(wh+ks*32), a2, 0,0,0);
        if (lh < 2){
            #pragma unroll
            for (int r=0;r<4;r++){
                int s = lh*4+r;
                g1[s*768 + n0 + lr] = a1[r];
                g2[s*768 + n0 + lr] = a2[r];
            }
        }
    }
}

// ---------------- tail: combine -> MFMA GEMM chain -> slots (+prep) ----------------
__global__ __launch_bounds__(256) void k_tail(
    const float* __restrict__ pacc, const float* __restrict__ ppsum,
    const float* __restrict__ pmax, const float* __restrict__ slots,
    const _Float16* __restrict__ Wv16, const float* __restrict__ bv,
    const _Float16* __restrict__ Wih16, const float* __restrict__ bih,
    const _Float16* __restrict__ Whh16, const float* __restrict__ bhh,
    const _Float16* __restrict__ W116, const float* __restrict__ b1,
    const _Float16* __restrict__ W216, const float* __restrict__ b2,
    const float* __restrict__ gm, const float* __restrict__ bem,
    const float* __restrict__ g_sl, const float* __restrict__ be_sl,
    const _Float16* __restrict__ Wq16, const float* __restrict__ bq,
    const _Float16* __restrict__ WkT16,
    float* __restrict__ out, _Float16* __restrict__ qh16, int last) {
    int t = threadIdx.x, w = t>>6, l = t&63;
    int b = blockIdx.x;
    __shared__ float ax[8][256], hb[8][256], hn[8][256];
    __shared__ float g1[8*768], g2[8*768];
    __shared__ _Float16 a16a[16*256], a16b[16*256];
    __shared__ float pss[8], Mg[8];
    __shared__ float wcs[8][8];
    __shared__ float2 mv[8];

    // zero pad rows 8..15 of both A-tiles (once)
    {
        float4 z = {0.f,0.f,0.f,0.f};
        #pragma unroll
        for (int it=0; it<2; ++it){
            int row = 8 + it*4 + w;
            a16_st4(a16a, row, l*4, z);
            a16_st4(a16b, row, l*4, z);
        }
    }
    // ---- combine partials ----
    if (t<8){
        float M=-1e30f;
        for (int c=0;c<8;c++) M = fmaxf(M, pmax[((long)b*8+c)*8+t]);
        Mg[t]=M;
    }
    __syncthreads();
    if (t<64){
        int s=t>>3, c=t&7;
        wcs[s][c] = __expf(pmax[((long)b*8+c)*8+s] - Mg[s]);
    }
    __syncthreads();
    if (t<8){
        float v=0.f;
        for (int c=0;c<8;c++) v += wcs[t][c]*ppsum[((long)b*8+c)*8+t];
        pss[t]=v;
    }
    __syncthreads();
    #pragma unroll
    for (int s=0;s<8;s++){
        float v=0.f;
        for (int c=0;c<8;c++) v += wcs[s][c]*pacc[(((long)b*8+c)*8+s)*D_ + t];
        ax[s][t] = v / pss[s];
        hb[s][t] = slots[((long)b*8+s)*D_ + t];
    }
    __syncthreads();
    // conv: a16a <- ax, a16b <- hb
    #pragma unroll
    for (int it=0; it<2; ++it){
        int row = it*4 + w; int col = l*4;
        a16_st4(a16a, row, col, *(const float4*)&ax[row][col]);
        a16_st4(a16b, row, col, *(const float4*)&hb[row][col]);
    }
    __syncthreads();
    // us_raw = ax @ Wv^T  -> g1[8][256]
    mm_stage<4,256>(a16a, Wv16, g1, w, l);
    __syncthreads();
    // a16a <- us = us_raw + bv
    #pragma unroll
    for (int it=0; it<2; ++it){
        int row = it*4 + w; int col = l*4;
        float4 v = *(const float4*)&g1[row*256+col];
        float4 bb = *(const float4*)&bv[col];
        v.x+=bb.x; v.y+=bb.y; v.z+=bb.z; v.w+=bb.w;
        a16_st4(a16a, row, col, v);
    }
    __syncthreads();
    // gates
    mm_gates(a16a, a16b, Wih16, Whh16, g1, g2, w, l);
    __syncthreads();
    // GRU elementwise -> hn
    {
        float bi0=bih[t], bi1=bih[256+t], bi2=bih[512+t];
        float bh0=bhh[t], bh1=bhh[256+t], bh2=bhh[512+t];
        #pragma unroll
        for (int s=0;s<8;s++){
            float xr=g1[s*768+t],     hr=g2[s*768+t];
            float xz=g1[s*768+256+t], hz=g2[s*768+256+t];
            float xg=g1[s*768+512+t], hg=g2[s*768+512+t];
            float r = 1.f/(1.f+__expf(-(xr+bi0+hr+bh0)));
            float z = 1.f/(1.f+__expf(-(xz+bi1+hz+bh1)));
            float nn = tanhf(xg+bi2 + r*(hg+bh2));
            hn[s][t] = (1.f-z)*nn + z*hb[s][t];
        }
    }
    __syncthreads();
    // LN(hn) -> a16a (with g_mlp/be_mlp)
    for (int rr = w*2; rr < w*2+2; rr++){
        float4 hv = *(const float4*)&hn[rr][l*4];
        float s1 = hv.x+hv.y+hv.z+hv.w;
        float s2 = hv.x*hv.x+hv.y*hv.y+hv.z*hv.z+hv.w*hv.w;
        #pragma unroll
        for (int m=1;m<64;m<<=1){ s1+=__shfl_xor(s1,m); s2+=__shfl_xor(s2,m);}
        if (l==0){ float mean=s1*(1.0f/D_); float var=s2*(1.0f/D_)-mean*mean;
                   mv[rr]=make_float2(mean, rsqrtf(var+EPSL)); }
    }
    __syncthreads();
    #pragma unroll
    for (int it=0; it<2; ++it){
        int row = it*4 + w; int col = l*4;
        float4 hv = *(const float4*)&hn[row][col];
        float4 gv = *(const float4*)&gm[col];
        float4 bb = *(const float4*)&bem[col];
        float mean = mv[row].x, inv = mv[row].y;
        float4 v;
        v.x=(hv.x-mean)*inv*gv.x+bb.x; v.y=(hv.y-mean)*inv*gv.y+bb.y;
        v.z=(hv.z-mean)*inv*gv.z+bb.z; v.w=(hv.w-mean)*inv*gv.w+bb.w;
        a16_st4(a16a, row, col, v);
    }
    __syncthreads();
    // hid_raw = ml @ W1^T -> g1
    mm_stage<4,256>(a16a, W116, g1, w, l);
    __syncthreads();
    // a16b <- relu(hid_raw + b1)
    #pragma unroll
    for (int it=0; it<2; ++it){
        int row = it*4 + w; int col = l*4;
        float4 v = *(const float4*)&g1[row*256+col];
        float4 bb = *(const float4*)&b1[col];
        v.x=fmaxf(v.x+bb.x,0.f); v.y=fmaxf(v.y+bb.y,0.f);
        v.z=fmaxf(v.z+bb.z,0.f); v.w=fmaxf(v.w+bb.w,0.f);
        a16_st4(a16b, row, col, v);
    }
    __syncthreads();
    // o_raw = hid @ W2^T -> g2
    mm_stage<4,256>(a16b, W216, g2, w, l);
    __syncthreads();
    // o = hn + o_raw + b2 -> out (and ax for next-LN if !last)
    {
        float b2t = b2[t];
        #pragma unroll
        for (int s=0;s<8;s++){
            float o = hn[s][t] + g2[s*256+t] + b2t;
            out[((long)b*8+s)*D_ + t] = o;
            ax[s][t] = o;
        }
    }
    if (last) return;
    __syncthreads();
    // LN_sl(o) -> a16a
    for (int rr = w*2; rr < w*2+2; rr++){
        float4 hv = *(const float4*)&ax[rr][l*4];
        float s1 = hv.x+hv.y+hv.z+hv.w;
        float s2 = hv.x*hv.x+hv.y*hv.y+hv.z*hv.z+hv.w*hv.w;
        #pragma unroll
        for (int m=1;m<64;m<<=1){ s1+=__shfl_xor(s1,m); s2+=__shfl_xor(s2,m);}
        if (l==0){ float mean=s1*(1.0f/D_); float var=s2*(1.0f/D_)-mean*mean;
                   mv[rr]=make_float2(mean, rsqrtf(var+EPSL)); }
    }
    __syncthreads();
    #pragma unroll
    for (int it=0; it<2; ++it){
        int row = it*4 + w; int col = l*4;
        float4 hv = *(const float4*)&ax[row][col];
        float4 gv = *(const float4*)&g_sl[col];
        float4 bb = *(const float4*)&be_sl[col];
        float mean = mv[row].x, inv = mv[row].y;
        float4 v;
        v.x=(hv.x-mean)*inv*gv.x+bb.x; v.y=(hv.y-mean)*inv*gv.y+bb.y;
        v.z=(hv.z-mean)*inv*gv.z+bb.z; v.w=(hv.w-mean)*inv*gv.w+bb.w;
        a16_st4(a16a, row, col, v);
    }
    __syncthreads();
    // q_raw = sn @ Wq^T -> g1
    mm_stage<4,256>(a16a, Wq16, g1, w, l);
    __syncthreads();
    // a16b <- q = q_raw + bq
    #pragma unroll
    for (int it=0; it<2; ++it){
        int row = it*4 + w; int col = l*4;
        float4 v = *(const float4*)&g1[row*256+col];
        float4 bb = *(const float4*)&bq[col];
        v.x+=bb.x; v.y+=bb.y; v.z+=bb.z; v.w+=bb.w;
        a16_st4(a16b, row, col, v);
    }
    __syncthreads();
    // qh = q @ Wk  (WkT rows) -> g2
    mm_stage<4,256>(a16b, WkT16, g2, w, l);
    __syncthreads();
    #pragma unroll
    for (int s=0;s<8;s++)
        qh16[((long)b*16+s)*D_ + t] = (_Float16)g2[s*256+t];
}

extern "C" void kernel_launch(void* const* d_in, const int* in_sizes, int n_in,
                              void* d_out, int out_size, void* d_ws, size_t ws_size,
                              hipStream_t stream) {
    const float* x     = (const float*)d_in[0];
    const float* noise = (const float*)d_in[1];
    const float* mu    = (const float*)d_in[2];
    const float* sg    = (const float*)d_in[3];
    const float* Wq    = (const float*)d_in[4];
    const float* bq    = (const float*)d_in[5];
    const float* Wk    = (const float*)d_in[6];
    // d_in[7] = bk: softmax-invariant, unused
    const float* Wv    = (const float*)d_in[8];
    const float* bv    = (const float*)d_in[9];
    const float* Wih   = (const float*)d_in[10];
    const float* bih   = (const float*)d_in[11];
    const float* Whh   = (const float*)d_in[12];
    const float* bhh   = (const float*)d_in[13];
    const float* W1    = (const float*)d_in[14];
    const float* b1    = (const float*)d_in[15];
    const float* W2    = (const float*)d_in[16];
    const float* b2    = (const float*)d_in[17];
    const float* g_in  = (const float*)d_in[18];
    const float* be_in = (const float*)d_in[19];
    const float* g_sl  = (const float*)d_in[20];
    const float* be_sl = (const float*)d_in[21];
    const float* g_mlp = (const float*)d_in[22];
    const float* be_mlp= (const float*)d_in[23];

    char* ws = (char*)d_ws;
    _Float16* xn16  = (_Float16*)(ws);                   // 134217728 B
    _Float16* qh16  = (_Float16*)(ws + 134217728);       //    524288 B
    float*    slots = (float*)   (ws + 134742016);       //    524288 B
    float*    pacc  = (float*)   (ws + 135266304);       //  16777216 B
    float*    ppsum = (float*)   (ws + 152043520);       //     16384 B
    float*    pmax  = (float*)   (ws + 152059904);       //     16384 B
    _Float16* w16   = (_Float16*)(ws + 152076288);       //   1441792 B (end ~153.5MB)

    _Float16* Wv16  = w16;
    _Float16* Wih16 = w16 + 65536;
    _Float16* Whh16 = w16 + 262144;
    _Float16* W116  = w16 + 458752;
    _Float16* W216  = w16 + 524288;
    _Float16* Wq16  = w16 + 589824;
    _Float16* WkT16 = w16 + 655360;

    hipLaunchKernelGGL(k_ln_x, dim3(65536), dim3(256), 0, stream, x, g_in, be_in, xn16);
    hipLaunchKernelGGL(k_wprep, dim3(2816), dim3(256), 0, stream,
                       Wv, Wih, Whh, W1, W2, Wq, Wk, w16);
    hipLaunchKernelGGL(k_slot_init, dim3(512), dim3(256), 0, stream, noise, mu, sg,
                       slots, (unsigned int*)qh16);
    hipLaunchKernelGGL(k_slotprep, dim3(512), dim3(256), 0, stream,
                       slots, g_sl, be_sl, Wq, bq, Wk, qh16);
    for (int it = 0; it < 3; it++){
        hipLaunchKernelGGL(k_attn, dim3(8,64), dim3(256), 0, stream,
                           xn16, qh16, pacc, ppsum, pmax);
        float* dst = (it==2) ? (float*)d_out : slots;
        hipLaunchKernelGGL(k_tail, dim3(64), dim3(256), 0, stream,
                           pacc, ppsum, pmax, slots,
                           Wv16, bv, Wih16, bih, Whh16, bhh,
                           W116, b1, W216, b2, g_mlp, be_mlp,
                           g_sl, be_sl, Wq16, bq, WkT16,
                           dst, qh16, (it==2) ? 1 : 0);
    }
}

// Round 4
// 373.792 us; speedup vs baseline: 1.7563x; 1.0451x over previous
//
#include <hip/hip_runtime.h>

#define B_ 64
#define N_ 4096
#define D_ 256
#define S_ 8
#define EPSL 1e-5f

typedef _Float16 f16x8 __attribute__((ext_vector_type(8)));
typedef _Float16 f16x4 __attribute__((ext_vector_type(4)));
typedef float f32x4 __attribute__((ext_vector_type(4)));

// ---------------- LN(x) -> xn fp16 ----------------
__global__ __launch_bounds__(256) void k_ln_x(const float* __restrict__ x,
        const float* __restrict__ g, const float* __restrict__ be,
        _Float16* __restrict__ xn) {
    int w = threadIdx.x >> 6, l = threadIdx.x & 63;
    long row = (long)blockIdx.x * 4 + w;   // < 262144
    float4 xv = *(const float4*)(x + row * D_ + l * 4);
    float s = xv.x + xv.y + xv.z + xv.w;
    float q = xv.x*xv.x + xv.y*xv.y + xv.z*xv.z + xv.w*xv.w;
    #pragma unroll
    for (int m = 1; m < 64; m <<= 1) { s += __shfl_xor(s, m); q += __shfl_xor(q, m); }
    float mean = s * (1.0f/D_);
    float var = q * (1.0f/D_) - mean*mean;
    float inv = rsqrtf(var + EPSL);
    float4 gv = *(const float4*)(g + l*4);
    float4 bv = *(const float4*)(be + l*4);
    f16x4 o;
    o[0] = (_Float16)((xv.x-mean)*inv*gv.x + bv.x);
    o[1] = (_Float16)((xv.y-mean)*inv*gv.y + bv.y);
    o[2] = (_Float16)((xv.z-mean)*inv*gv.z + bv.z);
    o[3] = (_Float16)((xv.w-mean)*inv*gv.w + bv.w);
    *(f16x4*)(xn + row * D_ + l*4) = o;
}

// ---------------- slots init + zero qh16 ----------------
__global__ __launch_bounds__(256) void k_slot_init(const float* __restrict__ noise,
        const float* __restrict__ mu, const float* __restrict__ sg,
        float* __restrict__ slots, unsigned int* __restrict__ qh_zero) {
    int tid = blockIdx.x*256 + threadIdx.x;  // < 131072
    int d = tid & 255;
    slots[tid] = mu[d] + __expf(sg[d]) * noise[tid];
    qh_zero[tid] = 0u;
}

// ---------------- weights -> f16 (and Wk transposed) ----------------
__global__ __launch_bounds__(256) void k_wprep(const float* __restrict__ Wv,
        const float* __restrict__ Wih, const float* __restrict__ Whh,
        const float* __restrict__ W1, const float* __restrict__ W2,
        const float* __restrict__ Wq, const float* __restrict__ Wk,
        _Float16* __restrict__ o) {
    long i = (long)blockIdx.x*256 + threadIdx.x;
    if (i < 65536)        o[i] = (_Float16)Wv[i];
    else if (i < 262144)  o[i] = (_Float16)Wih[i-65536];
    else if (i < 458752)  o[i] = (_Float16)Whh[i-262144];
    else if (i < 524288)  o[i] = (_Float16)W1[i-458752];
    else if (i < 589824)  o[i] = (_Float16)W2[i-524288];
    else if (i < 655360)  o[i] = (_Float16)Wq[i-589824];
    else if (i < 720896){ long j = i-655360; int d = (int)(j>>8), e = (int)(j&255);
                          o[i] = (_Float16)Wk[(long)e*256 + d]; }
}

// ---------------- initial per-slot: LN -> q -> qh (fp16) ----------------
__global__ __launch_bounds__(256) void k_slotprep(const float* __restrict__ slots,
     const float* __restrict__ g, const float* __restrict__ be,
     const float* __restrict__ Wq, const float* __restrict__ bq,
     const float* __restrict__ Wk, _Float16* __restrict__ qh16) {
    __shared__ float sn[D_], ql[D_], red[10];
    int t = threadIdx.x, w = t>>6, l = t&63;
    long base = (long)blockIdx.x * D_;
    float v = slots[base + t];
    float s = v, q = v*v;
    #pragma unroll
    for (int m=1;m<64;m<<=1){ s+=__shfl_xor(s,m); q+=__shfl_xor(q,m);}
    if (l==0){ red[w]=s; red[4+w]=q; }
    __syncthreads();
    if (t==0){
        float ss=red[0]+red[1]+red[2]+red[3];
        float qq=red[4]+red[5]+red[6]+red[7];
        float mean = ss*(1.0f/D_); float var = qq*(1.0f/D_) - mean*mean;
        red[8]=mean; red[9]=rsqrtf(var+EPSL);
    }
    __syncthreads();
    float mean=red[8], inv=red[9];
    sn[t] = (v-mean)*inv*g[t] + be[t];
    __syncthreads();
    float acc = bq[t];
    const float4* wr = (const float4*)(Wq + (long)t*D_);
    const float4* sv = (const float4*)sn;
    for (int e=0;e<64;e++){ float4 a=wr[e], b=sv[e];
        acc += a.x*b.x + a.y*b.y + a.z*b.z + a.w*b.w; }
    ql[t]=acc;
    __syncthreads();
    float qh=0.f;
    for (int e=0;e<D_;e++) qh += ql[e]*Wk[(long)e*D_ + t];
    qh16[((long)(blockIdx.x>>3)*16 + (blockIdx.x&7))*D_ + t] = (_Float16)qh;
}

// ---------------- fused: logits (MFMA) + online softmax + axpy ----------------
// All hot LDS (xt/pt) is PER-WAVE -> no per-sc __syncthreads; waves free-run.
#define XPAD 264
__global__ __launch_bounds__(256) void k_attn(const _Float16* __restrict__ xn,
        const _Float16* __restrict__ qh16,
        float* __restrict__ pacc, float* __restrict__ ppsum,
        float* __restrict__ pmax) {
    __shared__ _Float16 xt_s[4][16][XPAD];   // 33792 B, reused as accw f32[4][8][256]
    __shared__ float pt_s[4][16][8];
    __shared__ float mw_s[4][8];
    __shared__ float psw_s[4][8];
    int t = threadIdx.x, w = t>>6, l = t&63, lr = l&15, lh = l>>4;
    int c = blockIdx.x, b = blockIdx.y;

    f16x8 A[8];
    const _Float16* qbase = qh16 + ((long)b*16 + lr)*D_ + lh*8;
    #pragma unroll
    for (int ks=0;ks<8;ks++) A[ks] = *(const f16x8*)(qbase + ks*32);

    float m8[8];
    #pragma unroll
    for (int s=0;s<8;s++) m8[s] = -1e30f;
    float acc[8][4] = {};
    float psr[4] = {0.f,0.f,0.f,0.f};

    _Float16 (*xt)[XPAD] = xt_s[w];
    float (*pt)[8] = pt_s[w];

    for (int sc=0; sc<8; ++sc){
        int n0 = c*512 + sc*64 + w*16;
        const _Float16* xb = xn + ((long)b*N_ + n0 + lr)*D_ + lh*8;
        f32x4 lacc = {0.f,0.f,0.f,0.f};
        #pragma unroll
        for (int ks=0;ks<8;ks++){
            f16x8 Bf = *(const f16x8*)(xb + ks*32);
            *(f16x8*)&xt[lr][ks*32 + lh*8] = Bf;
            lacc = __builtin_amdgcn_mfma_f32_16x16x32_f16(A[ks], Bf, lacc, 0,0,0);
        }
        float tm[4];
        #pragma unroll
        for (int r=0;r<4;r++) tm[r] = lacc[r];
        #pragma unroll
        for (int m=1;m<16;m<<=1){
            #pragma unroll
            for (int r=0;r<4;r++) tm[r] = fmaxf(tm[r], __shfl_xor(tm[r], m));
        }
        float mN[8];
        #pragma unroll
        for (int r=0;r<4;r++){ mN[r] = __shfl(tm[r], lr); mN[4+r] = __shfl(tm[r], 16+lr); }
        float sc8[8];
        #pragma unroll
        for (int s=0;s<8;s++){
            float mn = fmaxf(m8[s], mN[s]);
            sc8[s] = __expf(m8[s] - mn);
            m8[s] = mn;
        }
        #pragma unroll
        for (int s=0;s<8;s++){
            acc[s][0]*=sc8[s]; acc[s][1]*=sc8[s]; acc[s][2]*=sc8[s]; acc[s][3]*=sc8[s];
        }
        if (lh < 2){
            float4 pv;
            #pragma unroll
            for (int r=0;r<4;r++){
                int s = lh*4+r;
                float p = __expf(lacc[r] - m8[s]);
                psr[r] = psr[r]*sc8[s] + p;
                ((float*)&pv)[r] = p;
            }
            *(float4*)&pt[lr][lh*4] = pv;
        }
        // no barrier: xt/pt are per-wave; wave-internal DS ordering suffices
        #pragma unroll 4
        for (int i=0;i<16;i++){
            float4 p0 = *(const float4*)&pt[i][0];
            float4 p1 = *(const float4*)&pt[i][4];
            f16x4 xv = *(const f16x4*)&xt[i][l*4];
            float x0=(float)xv[0], x1=(float)xv[1], x2=(float)xv[2], x3=(float)xv[3];
            acc[0][0]+=p0.x*x0; acc[0][1]+=p0.x*x1; acc[0][2]+=p0.x*x2; acc[0][3]+=p0.x*x3;
            acc[1][0]+=p0.y*x0; acc[1][1]+=p0.y*x1; acc[1][2]+=p0.y*x2; acc[1][3]+=p0.y*x3;
            acc[2][0]+=p0.z*x0; acc[2][1]+=p0.z*x1; acc[2][2]+=p0.z*x2; acc[2][3]+=p0.z*x3;
            acc[3][0]+=p0.w*x0; acc[3][1]+=p0.w*x1; acc[3][2]+=p0.w*x2; acc[3][3]+=p0.w*x3;
            acc[4][0]+=p1.x*x0; acc[4][1]+=p1.x*x1; acc[4][2]+=p1.x*x2; acc[4][3]+=p1.x*x3;
            acc[5][0]+=p1.y*x0; acc[5][1]+=p1.y*x1; acc[5][2]+=p1.y*x2; acc[5][3]+=p1.y*x3;
            acc[6][0]+=p1.z*x0; acc[6][1]+=p1.z*x1; acc[6][2]+=p1.z*x2; acc[6][3]+=p1.z*x3;
            acc[7][0]+=p1.w*x0; acc[7][1]+=p1.w*x1; acc[7][2]+=p1.w*x2; acc[7][3]+=p1.w*x3;
        }
    }
    #pragma unroll
    for (int m=1;m<16;m<<=1){
        #pragma unroll
        for (int r=0;r<4;r++) psr[r] += __shfl_xor(psr[r], m);
    }
    if (l == 0){
        #pragma unroll
        for (int s=0;s<8;s++) mw_s[w][s] = m8[s];
        #pragma unroll
        for (int r=0;r<4;r++) psw_s[w][r] = psr[r];
    }
    if (l == 16){
        #pragma unroll
        for (int r=0;r<4;r++) psw_s[w][4+r] = psr[r];
    }
    __syncthreads();
    float M8[8];
    #pragma unroll
    for (int s=0;s<8;s++)
        M8[s] = fmaxf(fmaxf(mw_s[0][s],mw_s[1][s]), fmaxf(mw_s[2][s],mw_s[3][s]));
    float* accw = (float*)xt_s;
    #pragma unroll
    for (int s=0;s<8;s++){
        float wsc = __expf(m8[s] - M8[s]);
        float4 v;
        v.x=acc[s][0]*wsc; v.y=acc[s][1]*wsc; v.z=acc[s][2]*wsc; v.w=acc[s][3]*wsc;
        *(float4*)&accw[((w*8+s)<<8) + l*4] = v;
    }
    __syncthreads();
    for (int pair=t; pair<2048; pair+=256){
        int s = pair>>8, d = pair&255;
        float v = accw[(s<<8)+d] + accw[((8+s)<<8)+d] + accw[((16+s)<<8)+d] + accw[((24+s)<<8)+d];
        pacc[(((long)b*8 + c)*8 + s)*D_ + d] = v;
    }
    if (t < 8){
        float ps = 0.f;
        #pragma unroll
        for (int w2=0;w2<4;w2++) ps += __expf(mw_s[w2][t]-M8[t]) * psw_s[w2][t];
        ppsum[((long)b*8+c)*8 + t] = ps;
        pmax [((long)b*8+c)*8 + t] = M8[t];
    }
}

// ============ tail helpers: swizzled f16 A-tile in LDS ============
__device__ __forceinline__ void a16_st4(_Float16* a, int row, int col, float4 v){
    int byte = row*512 + ((col*2) ^ ((row&7)<<4));
    f16x4 h; h[0]=(_Float16)v.x; h[1]=(_Float16)v.y; h[2]=(_Float16)v.z; h[3]=(_Float16)v.w;
    *(f16x4*)((char*)a + byte) = h;
}
__device__ __forceinline__ f16x8 a16_ld8(const _Float16* a, int row, int col){
    int byte = row*512 + ((col*2) ^ ((row&7)<<4));
    return *(const f16x8*)((const char*)a + byte);
}

// out[s][n] = sum_k A[s][k]*W[n][k]; 8 waves, N = 8*NT*16
template<int NT, int OS>
__device__ __forceinline__ void mm_stage(const _Float16* a16,
        const _Float16* __restrict__ Wg, float* outl, int w, int l){
    int lr = l&15, lh = l>>4;
    f16x8 A[8];
    #pragma unroll
    for (int ks=0;ks<8;ks++) A[ks] = a16_ld8(a16, lr, lh*8 + ks*32);
    #pragma unroll
    for (int tile=0; tile<NT; ++tile){
        int n0 = (w*NT + tile)*16;
        const _Float16* wb = Wg + (long)(n0+lr)*256 + lh*8;
        f32x4 acc = {0.f,0.f,0.f,0.f};
        #pragma unroll
        for (int ks=0;ks<8;ks++){
            f16x8 Bf = *(const f16x8*)(wb + ks*32);
            acc = __builtin_amdgcn_mfma_f32_16x16x32_f16(A[ks], Bf, acc, 0,0,0);
        }
        if (lh < 2){
            #pragma unroll
            for (int r=0;r<4;r++) outl[(lh*4+r)*OS + n0 + lr] = acc[r];
        }
    }
}

// gates: g1 = us@Wih^T, g2 = hb@Whh^T  (N=768 each, K=256); 8 waves -> 6 tiles
__device__ __forceinline__ void mm_gates(const _Float16* au, const _Float16* ah,
        const _Float16* __restrict__ Wi, const _Float16* __restrict__ Wh,
        float* g1, float* g2, int w, int l){
    int lr = l&15, lh = l>>4;
    f16x8 Au[8], Ah[8];
    #pragma unroll
    for (int ks=0;ks<8;ks++){ Au[ks] = a16_ld8(au, lr, lh*8+ks*32);
                              Ah[ks] = a16_ld8(ah, lr, lh*8+ks*32); }
    #pragma unroll
    for (int tile=0; tile<6; ++tile){
        int n0 = (w*6 + tile)*16;
        const _Float16* wi = Wi + (long)(n0+lr)*256 + lh*8;
        const _Float16* wh = Wh + (long)(n0+lr)*256 + lh*8;
        f32x4 a1 = {0.f,0.f,0.f,0.f}, a2 = {0.f,0.f,0.f,0.f};
        #pragma unroll
        for (int ks=0;ks<8;ks++)
            a1 = __builtin_amdgcn_mfma_f32_16x16x32_f16(Au[ks], *(const f16x8*)(wi+ks*32), a1, 0,0,0);
        #pragma unroll
        for (int ks=0;ks<8;ks++)
            a2 = __builtin_amdgcn_mfma_f32_16x16x32_f16(Ah[ks], *(const f16x8*)(wh+ks*32), a2, 0,0,0);
        if (lh < 2){
            #pragma unroll
            for (int r=0;r<4;r++){
                int s = lh*4+r;
                g1[s*768 + n0 + lr] = a1[r];
                g2[s*768 + n0 + lr] = a2[r];
            }
        }
    }
}

// ---------------- tail: 512 threads, 8 waves ----------------
__global__ __launch_bounds__(512) void k_tail(
    const float* __restrict__ pacc, const float* __restrict__ ppsum,
    const float* __restrict__ pmax, const float* __restrict__ slots,
    const _Float16* __restrict__ Wv16, const float* __restrict__ bv,
    const _Float16* __restrict__ Wih16, const float* __restrict__ bih,
    const _Float16* __restrict__ Whh16, const float* __restrict__ bhh,
    const _Float16* __restrict__ W116, const float* __restrict__ b1,
    const _Float16* __restrict__ W216, const float* __restrict__ b2,
    const float* __restrict__ gm, const float* __restrict__ bem,
    const float* __restrict__ g_sl, const float* __restrict__ be_sl,
    const _Float16* __restrict__ Wq16, const float* __restrict__ bq,
    const _Float16* __restrict__ WkT16,
    float* __restrict__ out, _Float16* __restrict__ qh16, int last) {
    int t = threadIdx.x, w = t>>6, l = t&63;
    int b = blockIdx.x;
    __shared__ float ax[8][256], hb[8][256], hn[8][256];
    __shared__ float g1[8*768], g2[8*768];
    __shared__ _Float16 a16a[16*256], a16b[16*256];
    __shared__ float pss[8], Mg[8];
    __shared__ float wcs[8][8];
    __shared__ float2 mv[8];

    // zero pad rows 8..15 of both A-tiles (one st4 per thread per array)
    {
        float4 z = {0.f,0.f,0.f,0.f};
        a16_st4(a16a, 8+w, l*4, z);
        a16_st4(a16b, 8+w, l*4, z);
    }
    // ---- combine partials ----
    if (t<8){
        float M=-1e30f;
        for (int c=0;c<8;c++) M = fmaxf(M, pmax[((long)b*8+c)*8+t]);
        Mg[t]=M;
    }
    __syncthreads();
    if (t<64){
        int s=t>>3, c=t&7;
        wcs[s][c] = __expf(pmax[((long)b*8+c)*8+s] - Mg[s]);
    }
    __syncthreads();
    if (t<8){
        float v=0.f;
        for (int c=0;c<8;c++) v += wcs[t][c]*ppsum[((long)b*8+c)*8+t];
        pss[t]=v;
    }
    __syncthreads();
    for (int idx=t; idx<2048; idx+=512){
        int s = idx>>8, d = idx&255;
        float v=0.f;
        #pragma unroll
        for (int c=0;c<8;c++) v += wcs[s][c]*pacc[(((long)b*8+c)*8+s)*D_ + d];
        ax[s][d] = v / pss[s];
        hb[s][d] = slots[((long)b*8+s)*D_ + d];
    }
    __syncthreads();
    // a16a <- ax, a16b <- hb (row = w, col = l*4)
    a16_st4(a16a, w, l*4, *(const float4*)&ax[w][l*4]);
    a16_st4(a16b, w, l*4, *(const float4*)&hb[w][l*4]);
    __syncthreads();
    // us_raw = ax @ Wv^T -> g1[8][256]
    mm_stage<2,256>(a16a, Wv16, g1, w, l);
    __syncthreads();
    // a16a <- us = us_raw + bv
    {
        int col = l*4;
        float4 v = *(const float4*)&g1[w*256+col];
        float4 bb = *(const float4*)&bv[col];
        v.x+=bb.x; v.y+=bb.y; v.z+=bb.z; v.w+=bb.w;
        a16_st4(a16a, w, col, v);
    }
    __syncthreads();
    mm_gates(a16a, a16b, Wih16, Whh16, g1, g2, w, l);
    __syncthreads();
    // GRU elementwise -> hn
    for (int idx=t; idx<2048; idx+=512){
        int s = idx>>8, d = idx&255;
        float xr=g1[s*768+d],     hr=g2[s*768+d];
        float xz=g1[s*768+256+d], hz=g2[s*768+256+d];
        float xg=g1[s*768+512+d], hg=g2[s*768+512+d];
        float r = 1.f/(1.f+__expf(-(xr+bih[d]+hr+bhh[d])));
        float z = 1.f/(1.f+__expf(-(xz+bih[256+d]+hz+bhh[256+d])));
        float nn = tanhf(xg+bih[512+d] + r*(hg+bhh[512+d]));
        hn[s][d] = (1.f-z)*nn + z*hb[s][d];
    }
    __syncthreads();
    // LN(hn): wave w owns row w
    {
        float4 hv = *(const float4*)&hn[w][l*4];
        float s1 = hv.x+hv.y+hv.z+hv.w;
        float s2 = hv.x*hv.x+hv.y*hv.y+hv.z*hv.z+hv.w*hv.w;
        #pragma unroll
        for (int m=1;m<64;m<<=1){ s1+=__shfl_xor(s1,m); s2+=__shfl_xor(s2,m);}
        if (l==0){ float mean=s1*(1.0f/D_); float var=s2*(1.0f/D_)-mean*mean;
                   mv[w]=make_float2(mean, rsqrtf(var+EPSL)); }
    }
    __syncthreads();
    {
        int col = l*4;
        float4 hv = *(const float4*)&hn[w][col];
        float4 gv = *(const float4*)&gm[col];
        float4 bb = *(const float4*)&bem[col];
        float mean = mv[w].x, inv = mv[w].y;
        float4 v;
        v.x=(hv.x-mean)*inv*gv.x+bb.x; v.y=(hv.y-mean)*inv*gv.y+bb.y;
        v.z=(hv.z-mean)*inv*gv.z+bb.z; v.w=(hv.w-mean)*inv*gv.w+bb.w;
        a16_st4(a16a, w, col, v);
    }
    __syncthreads();
    mm_stage<2,256>(a16a, W116, g1, w, l);
    __syncthreads();
    {
        int col = l*4;
        float4 v = *(const float4*)&g1[w*256+col];
        float4 bb = *(const float4*)&b1[col];
        v.x=fmaxf(v.x+bb.x,0.f); v.y=fmaxf(v.y+bb.y,0.f);
        v.z=fmaxf(v.z+bb.z,0.f); v.w=fmaxf(v.w+bb.w,0.f);
        a16_st4(a16b, w, col, v);
    }
    __syncthreads();
    mm_stage<2,256>(a16b, W216, g2, w, l);
    __syncthreads();
    for (int idx=t; idx<2048; idx+=512){
        int s = idx>>8, d = idx&255;
        float o = hn[s][d] + g2[s*256+d] + b2[d];
        out[((long)b*8+s)*D_ + d] = o;
        ax[s][d] = o;
    }
    if (last) return;
    __syncthreads();
    // LN_sl(o) -> a16a
    {
        float4 hv = *(const float4*)&ax[w][l*4];
        float s1 = hv.x+hv.y+hv.z+hv.w;
        float s2 = hv.x*hv.x+hv.y*hv.y+hv.z*hv.z+hv.w*hv.w;
        #pragma unroll
        for (int m=1;m<64;m<<=1){ s1+=__shfl_xor(s1,m); s2+=__shfl_xor(s2,m);}
        if (l==0){ float mean=s1*(1.0f/D_); float var=s2*(1.0f/D_)-mean*mean;
                   mv[w]=make_float2(mean, rsqrtf(var+EPSL)); }
    }
    __syncthreads();
    {
        int col = l*4;
        float4 hv = *(const float4*)&ax[w][col];
        float4 gv = *(const float4*)&g_sl[col];
        float4 bb = *(const float4*)&be_sl[col];
        float mean = mv[w].x, inv = mv[w].y;
        float4 v;
        v.x=(hv.x-mean)*inv*gv.x+bb.x; v.y=(hv.y-mean)*inv*gv.y+bb.y;
        v.z=(hv.z-mean)*inv*gv.z+bb.z; v.w=(hv.w-mean)*inv*gv.w+bb.w;
        a16_st4(a16a, w, col, v);
    }
    __syncthreads();
    mm_stage<2,256>(a16a, Wq16, g1, w, l);
    __syncthreads();
    {
        int col = l*4;
        float4 v = *(const float4*)&g1[w*256+col];
        float4 bb = *(const float4*)&bq[col];
        v.x+=bb.x; v.y+=bb.y; v.z+=bb.z; v.w+=bb.w;
        a16_st4(a16b, w, col, v);
    }
    __syncthreads();
    mm_stage<2,256>(a16b, WkT16, g2, w, l);
    __syncthreads();
    for (int idx=t; idx<2048; idx+=512){
        int s = idx>>8, d = idx&255;
        qh16[((long)b*16+s)*D_ + d] = (_Float16)g2[s*256+d];
    }
}

extern "C" void kernel_launch(void* const* d_in, const int* in_sizes, int n_in,
                              void* d_out, int out_size, void* d_ws, size_t ws_size,
                              hipStream_t stream) {
    const float* x     = (const float*)d_in[0];
    const float* noise = (const float*)d_in[1];
    const float* mu    = (const float*)d_in[2];
    const float* sg    = (const float*)d_in[3];
    const float* Wq    = (const float*)d_in[4];
    const float* bq    = (const float*)d_in[5];
    const float* Wk    = (const float*)d_in[6];
    const float* Wv    = (const float*)d_in[8];
    const float* bv    = (const float*)d_in[9];
    const float* Wih   = (const float*)d_in[10];
    const float* bih   = (const float*)d_in[11];
    const float* Whh   = (const float*)d_in[12];
    const float* bhh   = (const float*)d_in[13];
    const float* W1    = (const float*)d_in[14];
    const float* b1    = (const float*)d_in[15];
    const float* W2    = (const float*)d_in[16];
    const float* b2    = (const float*)d_in[17];
    const float* g_in  = (const float*)d_in[18];
    const float* be_in = (const float*)d_in[19];
    const float* g_sl  = (const float*)d_in[20];
    const float* be_sl = (const float*)d_in[21];
    const float* g_mlp = (const float*)d_in[22];
    const float* be_mlp= (const float*)d_in[23];

    char* ws = (char*)d_ws;
    _Float16* xn16  = (_Float16*)(ws);                   // 134217728 B
    _Float16* qh16  = (_Float16*)(ws + 134217728);       //    524288 B
    float*    slots = (float*)   (ws + 134742016);       //    524288 B
    float*    pacc  = (float*)   (ws + 135266304);       //  16777216 B
    float*    ppsum = (float*)   (ws + 152043520);       //     16384 B
    float*    pmax  = (float*)   (ws + 152059904);       //     16384 B
    _Float16* w16   = (_Float16*)(ws + 152076288);       //   1441792 B

    _Float16* Wv16  = w16;
    _Float16* Wih16 = w16 + 65536;
    _Float16* Whh16 = w16 + 262144;
    _Float16* W116  = w16 + 458752;
    _Float16* W216  = w16 + 524288;
    _Float16* Wq16  = w16 + 589824;
    _Float16* WkT16 = w16 + 655360;

    hipLaunchKernelGGL(k_ln_x, dim3(65536), dim3(256), 0, stream, x, g_in, be_in, xn16);
    hipLaunchKernelGGL(k_wprep, dim3(2816), dim3(256), 0, stream,
                       Wv, Wih, Whh, W1, W2, Wq, Wk, w16);
    hipLaunchKernelGGL(k_slot_init, dim3(512), dim3(256), 0, stream, noise, mu, sg,
                       slots, (unsigned int*)qh16);
    hipLaunchKernelGGL(k_slotprep, dim3(512), dim3(256), 0, stream,
                       slots, g_sl, be_sl, Wq, bq, Wk, qh16);
    for (int it = 0; it < 3; it++){
        hipLaunchKernelGGL(k_attn, dim3(8,64), dim3(256), 0, stream,
                           xn16, qh16, pacc, ppsum, pmax);
        float* dst = (it==2) ? (float*)d_out : slots;
        hipLaunchKernelGGL(k_tail, dim3(64), dim3(512), 0, stream,
                           pacc, ppsum, pmax, slots,
                           Wv16, bv, Wih16, bih, Whh16, bhh,
                           W116, b1, W216, b2, g_mlp, be_mlp,
                           g_sl, be_sl, Wq16, bq, WkT16,
                           dst, qh16, (it==2) ? 1 : 0);
    }
}

// Round 5
// 273.597 us; speedup vs baseline: 2.3995x; 1.3662x over previous
//
#include <hip/hip_runtime.h>

#define B_ 64
#define N_ 4096
#define D_ 256
#define S_ 8
#define EPSL 1e-5f

typedef _Float16 f16x8 __attribute__((ext_vector_type(8)));
typedef _Float16 f16x4 __attribute__((ext_vector_type(4)));
typedef float f32x4 __attribute__((ext_vector_type(4)));

__device__ __forceinline__ void gload_lds16(const void* g, void* l){
    __builtin_amdgcn_global_load_lds(
        (const __attribute__((address_space(1))) unsigned int*)g,
        (__attribute__((address_space(3))) unsigned int*)l, 16, 0, 0);
}

// ---------------- LN(x) -> xn fp16 (row-major) ----------------
__global__ __launch_bounds__(256) void k_ln_x(const float* __restrict__ x,
        const float* __restrict__ g, const float* __restrict__ be,
        _Float16* __restrict__ xn) {
    int w = threadIdx.x >> 6, l = threadIdx.x & 63;
    long row = (long)blockIdx.x * 4 + w;
    float4 xv = *(const float4*)(x + row * D_ + l * 4);
    float s = xv.x + xv.y + xv.z + xv.w;
    float q = xv.x*xv.x + xv.y*xv.y + xv.z*xv.z + xv.w*xv.w;
    #pragma unroll
    for (int m = 1; m < 64; m <<= 1) { s += __shfl_xor(s, m); q += __shfl_xor(q, m); }
    float mean = s * (1.0f/D_);
    float var = q * (1.0f/D_) - mean*mean;
    float inv = rsqrtf(var + EPSL);
    float4 gv = *(const float4*)(g + l*4);
    float4 bv = *(const float4*)(be + l*4);
    f16x4 o;
    o[0] = (_Float16)((xv.x-mean)*inv*gv.x + bv.x);
    o[1] = (_Float16)((xv.y-mean)*inv*gv.y + bv.y);
    o[2] = (_Float16)((xv.z-mean)*inv*gv.z + bv.z);
    o[3] = (_Float16)((xv.w-mean)*inv*gv.w + bv.w);
    *(f16x4*)(xn + row * D_ + l*4) = o;
}

// ---------------- repack Whh,W1,W2 -> f16 fragment-linear ----------------
// frag index for (row, col) within a matrix:
//   (((row>>4)*8 + (col>>5))*64 + ((col>>3)&3)*16 + (row&15))*8 + (col&7)
__global__ __launch_bounds__(256) void k_wprep(const float* __restrict__ Whh,
        const float* __restrict__ W1, const float* __restrict__ W2,
        _Float16* __restrict__ Whhf, _Float16* __restrict__ W1f,
        _Float16* __restrict__ W2f) {
    int r = blockIdx.x, t = threadIdx.x;
    const float* src; _Float16* dst; int row;
    if (r < 768){ src = Whh; dst = Whhf; row = r; }
    else if (r < 1024){ src = W1; dst = W1f; row = r - 768; }
    else { src = W2; dst = W2f; row = r - 1024; }
    float v = src[(long)(r < 768 ? r : (r < 1024 ? r-768 : r-1024))*256 + t];
    long di = (long)((((row>>4)*8 + (t>>5))*64 + ((t>>3)&3)*16 + (row&15)))*8 + (t&7);
    dst[di] = (_Float16)v;
}

// ---------------- composite weights: Wc = Wih@Wv (768x256), Wqk = Wk^T@Wq-ish ----
// Wqk[d][j] = sum_e Wk[e][d]*Wq[e][j];  bc = Wih@bv + bih;  cq[d] = sum_e bq[e]Wk[e][d]
__global__ __launch_bounds__(256) void k_wprep2(const float* __restrict__ Wih,
        const float* __restrict__ Wv, const float* __restrict__ Wq,
        const float* __restrict__ Wk, const float* __restrict__ bih,
        const float* __restrict__ bv, const float* __restrict__ bq,
        _Float16* __restrict__ Wcf, _Float16* __restrict__ Wqkf,
        float* __restrict__ bc, float* __restrict__ cq) {
    __shared__ float a[4][256];
    int r = blockIdx.x, t = threadIdx.x;
    int w = t>>6, l = t&63;
    bool isC = (r < 192);
    if (isC){
        #pragma unroll
        for (int k=0;k<4;k++) a[k][t] = Wih[(long)(r*4+k)*256 + t];
    } else {
        int dbase = (r-192)*4;
        #pragma unroll
        for (int k=0;k<4;k++) a[k][t] = Wk[(long)t*256 + dbase + k];
    }
    __syncthreads();
    float ac[4] = {0.f,0.f,0.f,0.f};
    const float* Bm = isC ? Wv : Wq;
    for (int e=0;e<256;e++){
        float bvv = Bm[(long)e*256 + t];
        ac[0] += a[0][e]*bvv; ac[1] += a[1][e]*bvv;
        ac[2] += a[2][e]*bvv; ac[3] += a[3][e]*bvv;
    }
    _Float16* dst = isC ? Wcf : Wqkf;
    int rb = isC ? r*4 : (r-192)*4;
    #pragma unroll
    for (int k=0;k<4;k++){
        int row = rb + k;
        long di = (long)((((row>>4)*8 + (t>>5))*64 + ((t>>3)&3)*16 + (row&15)))*8 + (t&7);
        dst[di] = (_Float16)ac[k];
    }
    if (w < 4){
        const float* bvec = isC ? bv : bq;
        float p = 0.f;
        #pragma unroll
        for (int q=0;q<4;q++) p += a[w][l + q*64] * bvec[l + q*64];
        #pragma unroll
        for (int m=1;m<64;m<<=1) p += __shfl_xor(p, m);
        if (l==0){
            if (isC) bc[r*4 + w] = p + bih[r*4 + w];
            else     cq[(r-192)*4 + w] = p;
        }
    }
}

// ============ swizzled f16 A-tile in LDS ============
__device__ __forceinline__ void a16_st4(_Float16* a, int row, int col, float4 v){
    int byte = row*512 + ((col*2) ^ ((row&7)<<4));
    f16x4 h; h[0]=(_Float16)v.x; h[1]=(_Float16)v.y; h[2]=(_Float16)v.z; h[3]=(_Float16)v.w;
    *(f16x4*)((char*)a + byte) = h;
}
__device__ __forceinline__ void a16_st2(_Float16* a, int row, int col, _Float16 v){
    int byte = row*512 + ((col*2) ^ ((row&7)<<4));
    *(_Float16*)((char*)a + byte) = v;
}
__device__ __forceinline__ f16x8 a16_ld8(const _Float16* a, int row, int col){
    int byte = row*512 + ((col*2) ^ ((row&7)<<4));
    return *(const f16x8*)((const char*)a + byte);
}
__device__ __forceinline__ f16x8 wfrag_ld(const _Float16* __restrict__ Wf,
        int tt, int ks, int l){
    return *(const f16x8*)(Wf + ((long)tt*4096 + (ks*64 + l)*8));
}

// out[s][n] = sum_k A[s][k]*W[n][k]; 8 waves, N = 8*NT*16, frag-linear W
template<int NT, int OS>
__device__ __forceinline__ void mm_stage_f(const _Float16* a16,
        const _Float16* __restrict__ Wf, float* outl, int w, int l){
    int lr = l&15, lh = l>>4;
    f16x8 A[8];
    #pragma unroll
    for (int ks=0;ks<8;ks++) A[ks] = a16_ld8(a16, lr, lh*8 + ks*32);
    #pragma unroll
    for (int tile=0; tile<NT; ++tile){
        int tt = w*NT + tile;
        f32x4 acc = {0.f,0.f,0.f,0.f};
        #pragma unroll
        for (int ks=0;ks<8;ks++)
            acc = __builtin_amdgcn_mfma_f32_16x16x32_f16(A[ks], wfrag_ld(Wf,tt,ks,l), acc, 0,0,0);
        if (lh < 2){
            #pragma unroll
            for (int r=0;r<4;r++) outl[(lh*4+r)*OS + tt*16 + lr] = acc[r];
        }
    }
}

__device__ __forceinline__ void mm_gates_f(const _Float16* au, const _Float16* ah,
        const _Float16* __restrict__ Wcf, const _Float16* __restrict__ Whf,
        float* g1, float* g2, int w, int l){
    int lr = l&15, lh = l>>4;
    f16x8 Au[8], Ah[8];
    #pragma unroll
    for (int ks=0;ks<8;ks++){ Au[ks] = a16_ld8(au, lr, lh*8+ks*32);
                              Ah[ks] = a16_ld8(ah, lr, lh*8+ks*32); }
    #pragma unroll
    for (int tile=0; tile<6; ++tile){
        int tt = w*6 + tile;
        f32x4 a1 = {0.f,0.f,0.f,0.f}, a2 = {0.f,0.f,0.f,0.f};
        #pragma unroll
        for (int ks=0;ks<8;ks++)
            a1 = __builtin_amdgcn_mfma_f32_16x16x32_f16(Au[ks], wfrag_ld(Wcf,tt,ks,l), a1, 0,0,0);
        #pragma unroll
        for (int ks=0;ks<8;ks++)
            a2 = __builtin_amdgcn_mfma_f32_16x16x32_f16(Ah[ks], wfrag_ld(Whf,tt,ks,l), a2, 0,0,0);
        if (lh < 2){
            #pragma unroll
            for (int r=0;r<4;r++){
                int s = lh*4+r;
                g1[s*768 + tt*16 + lr] = a1[r];
                g2[s*768 + tt*16 + lr] = a2[r];
            }
        }
    }
}

// ---------------- init: slots + LN_sl -> qh via Wqk (replaces slot_init+slotprep) ---
__global__ __launch_bounds__(512) void k_init(const float* __restrict__ noise,
        const float* __restrict__ mu, const float* __restrict__ sg,
        const float* __restrict__ g_sl, const float* __restrict__ be_sl,
        const _Float16* __restrict__ Wqkf, const float* __restrict__ cq,
        float* __restrict__ slots, _Float16* __restrict__ qh16) {
    __shared__ __align__(16) _Float16 a16[16*256];
    __shared__ float g1[8*256];
    int t = threadIdx.x, w = t>>6, l = t&63, b = blockIdx.x;
    int col = l*4;
    float4 nz = *(const float4*)(noise + ((long)b*8+w)*256 + col);
    float4 muv = *(const float4*)(mu + col);
    float4 sgv = *(const float4*)(sg + col);
    float4 sl;
    sl.x = muv.x + __expf(sgv.x)*nz.x; sl.y = muv.y + __expf(sgv.y)*nz.y;
    sl.z = muv.z + __expf(sgv.z)*nz.z; sl.w = muv.w + __expf(sgv.w)*nz.w;
    *(float4*)(slots + ((long)b*8+w)*256 + col) = sl;
    float s1 = sl.x+sl.y+sl.z+sl.w;
    float s2 = sl.x*sl.x+sl.y*sl.y+sl.z*sl.z+sl.w*sl.w;
    #pragma unroll
    for (int m=1;m<64;m<<=1){ s1+=__shfl_xor(s1,m); s2+=__shfl_xor(s2,m); }
    float mean = s1*(1.0f/D_);
    float inv = rsqrtf(s2*(1.0f/D_) - mean*mean + EPSL);
    float4 gv = *(const float4*)(g_sl + col);
    float4 bb = *(const float4*)(be_sl + col);
    float4 sn;
    sn.x=(sl.x-mean)*inv*gv.x+bb.x; sn.y=(sl.y-mean)*inv*gv.y+bb.y;
    sn.z=(sl.z-mean)*inv*gv.z+bb.z; sn.w=(sl.w-mean)*inv*gv.w+bb.w;
    a16_st4(a16, w, col, sn);
    float4 z = {0.f,0.f,0.f,0.f};
    a16_st4(a16, 8+w, col, z);
    __syncthreads();
    mm_stage_f<2,256>(a16, Wqkf, g1, w, l);
    __syncthreads();
    for (int idx=t; idx<2048; idx+=512){
        int s = idx>>8, d = idx&255;
        qh16[((long)b*16+s)*D_ + d] = (_Float16)(g1[s*256+d] + cq[d]);
        qh16[((long)b*16+8+s)*D_ + d] = (_Float16)0.f;
    }
}

// ---------------- fused attn: glds-staged, dbuf, counted vmcnt, no K-loop barrier --
__global__ __launch_bounds__(256) void k_attn(const _Float16* __restrict__ xn,
        const _Float16* __restrict__ qh16,
        float* __restrict__ pacc, float* __restrict__ ppsum,
        float* __restrict__ pmax) {
    __shared__ __align__(16) char xt_raw[4*16384];   // per wave: 2 x 8 KB dbuf; reused as accw
    __shared__ __align__(16) float pt_s[4][16][8];
    __shared__ float mw_s[4][8], psw_s[4][8];
    int t = threadIdx.x, w = t>>6, l = t&63, lr = l&15, lh = l>>4;
    int c = blockIdx.x, b = blockIdx.y;

    f16x8 A[8];
    const _Float16* qbase = qh16 + ((long)b*16 + lr)*D_ + lh*8;
    #pragma unroll
    for (int ks=0;ks<8;ks++) A[ks] = *(const f16x8*)(qbase + ks*32);
    asm volatile("s_waitcnt vmcnt(0)" ::: "memory");

    char* xw = xt_raw + w*16384;
    const char* xnb = (const char*)(xn + (long)b*N_*D_);
    int rlo = l>>5;
    int cb  = (l&31)*16;

    {   // prologue: stage sc=0 into buf0
        int n0 = c*512 + w*16;
        #pragma unroll
        for (int j=0;j<8;j++){
            int row = 2*j + rlo;
            const char* gp = xnb + (long)(n0+row)*512 + (cb ^ ((row&7)<<4));
            gload_lds16(gp, xw + j*1024);
        }
    }

    float m8[8];
    #pragma unroll
    for (int s=0;s<8;s++) m8[s] = -1e30f;
    float acc[8][4] = {};
    float psr[4] = {0.f,0.f,0.f,0.f};
    float (*pt)[8] = pt_s[w];
    int fx = (lr&7)<<4;

    for (int sc=0; sc<8; ++sc){
        const char* curb = xw + ((sc&1)<<13);
        char* nxtb = xw + (((sc+1)&1)<<13);
        if (sc < 7){
            asm volatile("s_waitcnt lgkmcnt(0)" ::: "memory");  // prior phase-B reads of nxtb done
            int n0n = c*512 + (sc+1)*64 + w*16;
            #pragma unroll
            for (int j=0;j<8;j++){
                int row = 2*j + rlo;
                const char* gp = xnb + (long)(n0n+row)*512 + (cb ^ ((row&7)<<4));
                gload_lds16(gp, nxtb + j*1024);
            }
            asm volatile("s_waitcnt vmcnt(8)" ::: "memory");    // cur tile resident
        } else {
            asm volatile("s_waitcnt vmcnt(0)" ::: "memory");
        }
        __builtin_amdgcn_sched_barrier(0);

        f32x4 lacc = {0.f,0.f,0.f,0.f};
        #pragma unroll
        for (int ks=0;ks<8;ks++){
            f16x8 Bf = *(const f16x8*)(curb + lr*512 + ((lh*16 + ks*64) ^ fx));
            lacc = __builtin_amdgcn_mfma_f32_16x16x32_f16(A[ks], Bf, lacc, 0,0,0);
        }
        float tm[4];
        #pragma unroll
        for (int r=0;r<4;r++) tm[r] = lacc[r];
        #pragma unroll
        for (int m=1;m<16;m<<=1){
            #pragma unroll
            for (int r=0;r<4;r++) tm[r] = fmaxf(tm[r], __shfl_xor(tm[r], m));
        }
        float mN[8];
        #pragma unroll
        for (int r=0;r<4;r++){ mN[r] = __shfl(tm[r], lr); mN[4+r] = __shfl(tm[r], 16+lr); }
        float sc8[8];
        #pragma unroll
        for (int s=0;s<8;s++){
            float mn = fmaxf(m8[s], mN[s]);
            sc8[s] = __expf(m8[s] - mn);
            m8[s] = mn;
        }
        #pragma unroll
        for (int s=0;s<8;s++){
            acc[s][0]*=sc8[s]; acc[s][1]*=sc8[s]; acc[s][2]*=sc8[s]; acc[s][3]*=sc8[s];
        }
        if (lh < 2){
            float4 pv;
            #pragma unroll
            for (int r=0;r<4;r++){
                int s = lh*4+r;
                float p = __expf(lacc[r] - m8[s]);
                psr[r] = psr[r]*sc8[s] + p;
                ((float*)&pv)[r] = p;
            }
            *(float4*)&pt[lr][lh*4] = pv;
        }
        #pragma unroll 4
        for (int i=0;i<16;i++){
            float4 p0 = *(const float4*)&pt[i][0];
            float4 p1 = *(const float4*)&pt[i][4];
            f16x4 xv = *(const f16x4*)(curb + i*512 + ((l*8) ^ ((i&7)<<4)));
            float x0=(float)xv[0], x1=(float)xv[1], x2=(float)xv[2], x3=(float)xv[3];
            acc[0][0]+=p0.x*x0; acc[0][1]+=p0.x*x1; acc[0][2]+=p0.x*x2; acc[0][3]+=p0.x*x3;
            acc[1][0]+=p0.y*x0; acc[1][1]+=p0.y*x1; acc[1][2]+=p0.y*x2; acc[1][3]+=p0.y*x3;
            acc[2][0]+=p0.z*x0; acc[2][1]+=p0.z*x1; acc[2][2]+=p0.z*x2; acc[2][3]+=p0.z*x3;
            acc[3][0]+=p0.w*x0; acc[3][1]+=p0.w*x1; acc[3][2]+=p0.w*x2; acc[3][3]+=p0.w*x3;
            acc[4][0]+=p1.x*x0; acc[4][1]+=p1.x*x1; acc[4][2]+=p1.x*x2; acc[4][3]+=p1.x*x3;
            acc[5][0]+=p1.y*x0; acc[5][1]+=p1.y*x1; acc[5][2]+=p1.y*x2; acc[5][3]+=p1.y*x3;
            acc[6][0]+=p1.z*x0; acc[6][1]+=p1.z*x1; acc[6][2]+=p1.z*x2; acc[6][3]+=p1.z*x3;
            acc[7][0]+=p1.w*x0; acc[7][1]+=p1.w*x1; acc[7][2]+=p1.w*x2; acc[7][3]+=p1.w*x3;
        }
    }
    #pragma unroll
    for (int m=1;m<16;m<<=1){
        #pragma unroll
        for (int r=0;r<4;r++) psr[r] += __shfl_xor(psr[r], m);
    }
    if (l == 0){
        #pragma unroll
        for (int s=0;s<8;s++) mw_s[w][s] = m8[s];
        #pragma unroll
        for (int r=0;r<4;r++) psw_s[w][r] = psr[r];
    }
    if (l == 16){
        #pragma unroll
        for (int r=0;r<4;r++) psw_s[w][4+r] = psr[r];
    }
    __syncthreads();
    float M8[8];
    #pragma unroll
    for (int s=0;s<8;s++)
        M8[s] = fmaxf(fmaxf(mw_s[0][s],mw_s[1][s]), fmaxf(mw_s[2][s],mw_s[3][s]));
    float* accw = (float*)xt_raw;   // [4][8][256]
    #pragma unroll
    for (int s=0;s<8;s++){
        float wsc = __expf(m8[s] - M8[s]);
        float4 v;
        v.x=acc[s][0]*wsc; v.y=acc[s][1]*wsc; v.z=acc[s][2]*wsc; v.w=acc[s][3]*wsc;
        *(float4*)&accw[((w*8+s)<<8) + l*4] = v;
    }
    __syncthreads();
    for (int pair=t; pair<2048; pair+=256){
        int s = pair>>8, d = pair&255;
        float v = accw[(s<<8)+d] + accw[((8+s)<<8)+d] + accw[((16+s)<<8)+d] + accw[((24+s)<<8)+d];
        pacc[(((long)b*8 + c)*8 + s)*D_ + d] = v;
    }
    if (t < 8){
        float ps = 0.f;
        #pragma unroll
        for (int w2=0;w2<4;w2++) ps += __expf(mw_s[w2][t]-M8[t]) * psw_s[w2][t];
        ppsum[((long)b*8+c)*8 + t] = ps;
        pmax [((long)b*8+c)*8 + t] = M8[t];
    }
}

// ---------------- tail: combine -> gates(Wc,Whh) -> GRU+LN -> MLP -> out (+Wqk) ----
__global__ __launch_bounds__(512) void k_tail(
    const float* __restrict__ pacc, const float* __restrict__ ppsum,
    const float* __restrict__ pmax, const float* __restrict__ slots,
    const _Float16* __restrict__ Wcf, const float* __restrict__ bc,
    const _Float16* __restrict__ Whhf, const float* __restrict__ bhh,
    const _Float16* __restrict__ W1f, const float* __restrict__ b1,
    const _Float16* __restrict__ W2f, const float* __restrict__ b2,
    const float* __restrict__ gm, const float* __restrict__ bem,
    const float* __restrict__ g_sl, const float* __restrict__ be_sl,
    const _Float16* __restrict__ Wqkf, const float* __restrict__ cq,
    float* __restrict__ out, _Float16* __restrict__ qh16, int last) {
    int t = threadIdx.x, w = t>>6, l = t&63;
    int b = blockIdx.x;
    __shared__ float hb[8][256], hn[8][256];
    __shared__ float g1[8*768], g2[8*768];
    __shared__ __align__(16) _Float16 a16a[16*256], a16b[16*256];
    __shared__ float pss[8];
    __shared__ float wcs[8][8];

    // S1: combine scalars
    if (t < 8){
        float pm[8]; float M = -1e30f;
        #pragma unroll
        for (int c=0;c<8;c++){ pm[c] = pmax[((long)b*8+c)*8+t]; M = fmaxf(M, pm[c]); }
        float ps = 0.f;
        #pragma unroll
        for (int c=0;c<8;c++){
            float wc = __expf(pm[c]-M);
            wcs[t][c] = wc;
            ps += wc*ppsum[((long)b*8+c)*8+t];
        }
        pss[t] = ps;
    }
    __syncthreads();
    // S2: ax,hb -> f16 tiles (+ zero pad rows)
    for (int idx=t; idx<2048; idx+=512){
        int s = idx>>8, d = idx&255;
        float v = 0.f;
        #pragma unroll
        for (int c=0;c<8;c++) v += wcs[s][c]*pacc[(((long)b*8+c)*8+s)*D_ + d];
        float axv = v / pss[s];
        float hbv = slots[((long)b*8+s)*D_ + d];
        hb[s][d] = hbv;
        a16_st2(a16a, s, d, (_Float16)axv);
        a16_st2(a16b, s, d, (_Float16)hbv);
    }
    {   float4 z = {0.f,0.f,0.f,0.f};
        a16_st4(a16a, 8+w, l*4, z);
        a16_st4(a16b, 8+w, l*4, z);
    }
    __syncthreads();
    // S3: gates
    mm_gates_f(a16a, a16b, Wcf, Whhf, g1, g2, w, l);
    __syncthreads();
    // S4: GRU + LN(gm,bem) fused, wave w = row w
    {
        int d0 = l*4;
        float hn4[4];
        #pragma unroll
        for (int i=0;i<4;i++){
            int d = d0+i;
            float r = 1.f/(1.f+__expf(-(g1[w*768+d]     + bc[d]     + g2[w*768+d]     + bhh[d])));
            float z = 1.f/(1.f+__expf(-(g1[w*768+256+d] + bc[256+d] + g2[w*768+256+d] + bhh[256+d])));
            float gg = g1[w*768+512+d] + bc[512+d] + r*(g2[w*768+512+d] + bhh[512+d]);
            float e2 = __expf(2.f*gg);
            float nn = 1.f - 2.f/(e2+1.f);
            hn4[i] = (1.f-z)*nn + z*hb[w][d];
            hn[w][d] = hn4[i];
        }
        float s1 = hn4[0]+hn4[1]+hn4[2]+hn4[3];
        float s2 = hn4[0]*hn4[0]+hn4[1]*hn4[1]+hn4[2]*hn4[2]+hn4[3]*hn4[3];
        #pragma unroll
        for (int m=1;m<64;m<<=1){ s1+=__shfl_xor(s1,m); s2+=__shfl_xor(s2,m); }
        float mean = s1*(1.0f/D_);
        float inv = rsqrtf(s2*(1.0f/D_) - mean*mean + EPSL);
        float4 gv = *(const float4*)(gm + d0);
        float4 bb = *(const float4*)(bem + d0);
        float4 v;
        v.x=(hn4[0]-mean)*inv*gv.x+bb.x; v.y=(hn4[1]-mean)*inv*gv.y+bb.y;
        v.z=(hn4[2]-mean)*inv*gv.z+bb.z; v.w=(hn4[3]-mean)*inv*gv.w+bb.w;
        a16_st4(a16a, w, d0, v);
    }
    __syncthreads();
    // S5: W1
    mm_stage_f<2,256>(a16a, W1f, g1, w, l);
    __syncthreads();
    // S6: relu
    {
        int d0 = l*4;
        float4 v = *(const float4*)&g1[w*256+d0];
        float4 bb = *(const float4*)(b1 + d0);
        v.x=fmaxf(v.x+bb.x,0.f); v.y=fmaxf(v.y+bb.y,0.f);
        v.z=fmaxf(v.z+bb.z,0.f); v.w=fmaxf(v.w+bb.w,0.f);
        a16_st4(a16b, w, d0, v);
    }
    __syncthreads();
    // S7: W2
    mm_stage_f<2,256>(a16b, W2f, g2, w, l);
    __syncthreads();
    // S8: out = hn + W2out + b2; LN_sl -> a16a
    {
        int d0 = l*4;
        float4 bb = *(const float4*)(b2 + d0);
        float4 o4;
        o4.x = hn[w][d0]   + g2[w*256+d0]   + bb.x;
        o4.y = hn[w][d0+1] + g2[w*256+d0+1] + bb.y;
        o4.z = hn[w][d0+2] + g2[w*256+d0+2] + bb.z;
        o4.w = hn[w][d0+3] + g2[w*256+d0+3] + bb.w;
        *(float4*)(out + ((long)b*8+w)*D_ + d0) = o4;
        if (!last){
            float s1 = o4.x+o4.y+o4.z+o4.w;
            float s2 = o4.x*o4.x+o4.y*o4.y+o4.z*o4.z+o4.w*o4.w;
            #pragma unroll
            for (int m=1;m<64;m<<=1){ s1+=__shfl_xor(s1,m); s2+=__shfl_xor(s2,m); }
            float mean = s1*(1.0f/D_);
            float inv = rsqrtf(s2*(1.0f/D_) - mean*mean + EPSL);
            float4 gv = *(const float4*)(g_sl + d0);
            float4 be = *(const float4*)(be_sl + d0);
            float4 v;
            v.x=(o4.x-mean)*inv*gv.x+be.x; v.y=(o4.y-mean)*inv*gv.y+be.y;
            v.z=(o4.z-mean)*inv*gv.z+be.z; v.w=(o4.w-mean)*inv*gv.w+be.w;
            a16_st4(a16a, w, d0, v);
        }
    }
    if (last) return;
    __syncthreads();
    // S9: qh = sn @ Wqk + cq
    mm_stage_f<2,256>(a16a, Wqkf, g1, w, l);
    __syncthreads();
    for (int idx=t; idx<2048; idx+=512){
        int s = idx>>8, d = idx&255;
        qh16[((long)b*16+s)*D_ + d] = (_Float16)(g1[s*256+d] + cq[d]);
    }
}

extern "C" void kernel_launch(void* const* d_in, const int* in_sizes, int n_in,
                              void* d_out, int out_size, void* d_ws, size_t ws_size,
                              hipStream_t stream) {
    const float* x     = (const float*)d_in[0];
    const float* noise = (const float*)d_in[1];
    const float* mu    = (const float*)d_in[2];
    const float* sg    = (const float*)d_in[3];
    const float* Wq    = (const float*)d_in[4];
    const float* bq    = (const float*)d_in[5];
    const float* Wk    = (const float*)d_in[6];
    // d_in[7] = bk: softmax-invariant, unused
    const float* Wv    = (const float*)d_in[8];
    const float* bv    = (const float*)d_in[9];
    const float* Wih   = (const float*)d_in[10];
    const float* bih   = (const float*)d_in[11];
    const float* Whh   = (const float*)d_in[12];
    const float* bhh   = (const float*)d_in[13];
    const float* W1    = (const float*)d_in[14];
    const float* b1    = (const float*)d_in[15];
    const float* W2    = (const float*)d_in[16];
    const float* b2    = (const float*)d_in[17];
    const float* g_in  = (const float*)d_in[18];
    const float* be_in = (const float*)d_in[19];
    const float* g_sl  = (const float*)d_in[20];
    const float* be_sl = (const float*)d_in[21];
    const float* g_mlp = (const float*)d_in[22];
    const float* be_mlp= (const float*)d_in[23];

    char* ws = (char*)d_ws;
    _Float16* xn16  = (_Float16*)(ws);                   // 134217728 B
    _Float16* qh16  = (_Float16*)(ws + 134217728);       //    524288 B
    float*    slots = (float*)   (ws + 134742016);       //    524288 B
    float*    pacc  = (float*)   (ws + 135266304);       //  16777216 B
    float*    ppsum = (float*)   (ws + 152043520);       //     16384 B
    float*    pmax  = (float*)   (ws + 152059904);       //     16384 B
    _Float16* w16f  = (_Float16*)(ws + 152076288);       //   1179648 B
    float*    bc    = (float*)   (ws + 153255936);       //      3072 B
    float*    cq    = (float*)   (ws + 153259008);       //      1024 B

    _Float16* Wcf  = w16f;             // 768x256 frag
    _Float16* Whhf = w16f + 196608;    // 768x256 frag
    _Float16* W1f  = w16f + 393216;    // 256x256 frag
    _Float16* W2f  = w16f + 458752;    // 256x256 frag
    _Float16* Wqkf = w16f + 524288;    // 256x256 frag

    hipLaunchKernelGGL(k_wprep, dim3(1280), dim3(256), 0, stream,
                       Whh, W1, W2, Whhf, W1f, W2f);
    hipLaunchKernelGGL(k_wprep2, dim3(256), dim3(256), 0, stream,
                       Wih, Wv, Wq, Wk, bih, bv, bq, Wcf, Wqkf, bc, cq);
    hipLaunchKernelGGL(k_ln_x, dim3(65536), dim3(256), 0, stream, x, g_in, be_in, xn16);
    hipLaunchKernelGGL(k_init, dim3(64), dim3(512), 0, stream,
                       noise, mu, sg, g_sl, be_sl, Wqkf, cq, slots, qh16);
    for (int it = 0; it < 3; it++){
        hipLaunchKernelGGL(k_attn, dim3(8,64), dim3(256), 0, stream,
                           xn16, qh16, pacc, ppsum, pmax);
        float* dst = (it==2) ? (float*)d_out : slots;
        hipLaunchKernelGGL(k_tail, dim3(64), dim3(512), 0, stream,
                           pacc, ppsum, pmax, slots,
                           Wcf, bc, Whhf, bhh, W1f, b1, W2f, b2,
                           g_mlp, be_mlp, g_sl, be_sl, Wqkf, cq,
                           dst, qh16, (it==2) ? 1 : 0);
    }
}